// Round 10
// baseline (515.057 us; speedup 1.0000x reference)
//
#include <hip/hip_runtime.h>
#include <stdint.h>

typedef unsigned short u16;
typedef float f32x4 __attribute__((ext_vector_type(4)));
typedef __bf16 bf16x8 __attribute__((ext_vector_type(8)));
typedef u16 u16x8 __attribute__((ext_vector_type(8)));

#define NHEADS 16
#define NKV 4
#define HD 64
#define HDIM 1024
#define FDIM 2048
#define SLEN 1024
#define BATCH 4
#define TTOK 4096
#define NEXP 8
#define QKVO 1536
#define K2 2048
#define NREP 32

__device__ __forceinline__ u16 f2bf(float f) {
  union { float f; uint32_t u; } c; c.f = f;
  uint32_t u = c.u;
  return (u16)((u + 0x7FFFu + ((u >> 16) & 1u)) >> 16);
}
__device__ __forceinline__ float bf2f(u16 h) {
  union { uint32_t u; float f; } c; c.u = ((uint32_t)h) << 16; return c.f;
}
__device__ __forceinline__ void split2(float v, u16& h, u16& l) {
  h = f2bf(v);
  l = f2bf(v - bf2f(h));
}

__device__ __forceinline__ f32x4 mfma16(bf16x8 a, bf16x8 b, f32x4 c) {
  return __builtin_amdgcn_mfma_f32_16x16x32_bf16(a, b, c, 0, 0, 0);
}

__device__ __forceinline__ bf16x8 lds_frag(const u16* base) {
  u16x8 v = *(const u16x8*)base;
  return __builtin_bit_cast(bf16x8, v);
}

__device__ __forceinline__ void gload_lds16(const void* g, void* l) {
  __builtin_amdgcn_global_load_lds((const __attribute__((address_space(1))) void*)g,
                                   (__attribute__((address_space(3))) void*)l, 16, 0, 0);
}

// ---- fp32 weight [R][1024] -> split bf16 [R][2048] = [hi|lo] ----
__global__ __launch_bounds__(256)
void cvt_w2_kernel(const float* __restrict__ in, u16* __restrict__ out, int n4) {
  int i = blockIdx.x * blockDim.x + threadIdx.x;
  if (i >= n4) return;
  float4 v = ((const float4*)in)[i];
  int row = i >> 8;
  int c = (i & 255) * 4;
  ushort4 h, l;
  split2(v.x, h.x, l.x); split2(v.y, h.y, l.y);
  split2(v.z, h.z, l.z); split2(v.w, h.w, l.w);
  u16* orow = out + (size_t)row * K2 + c;
  *(ushort4*)(orow) = h;
  *(ushort4*)(orow + 1024) = l;
}

// ---- tiled transpose + convert: in [R][C] f32 -> out [C][R] bf16, z = expert ----
__global__ __launch_bounds__(256)
void transpose_cvt_kernel(const float* __restrict__ in, u16* __restrict__ out, int R, int C) {
  __shared__ float tile[32][33];
  size_t eoff = (size_t)blockIdx.z * (size_t)R * (size_t)C;
  in += eoff; out += eoff;
  int c0 = blockIdx.x * 32, r0 = blockIdx.y * 32;
  int tx = threadIdx.x, ty = threadIdx.y;
#pragma unroll
  for (int i = 0; i < 4; i++)
    tile[ty + i * 8][tx] = in[(size_t)(r0 + ty + i * 8) * C + c0 + tx];
  __syncthreads();
#pragma unroll
  for (int i = 0; i < 4; i++)
    out[(size_t)(c0 + ty + i * 8) * R + r0 + tx] = f2bf(tile[tx][ty + i * 8]);
}

// ---- LayerNorm: o2 ([hi|lo] 2048-wide) OR (obf single + of32) ----
__global__ __launch_bounds__(256)
void ln_kernel(const float* __restrict__ x, const float* __restrict__ w,
               const float* __restrict__ bias, u16* __restrict__ o2,
               u16* __restrict__ obf, float* __restrict__ of32) {
  int t = blockIdx.x, tid = threadIdx.x;
  int wid = tid >> 6, lane = tid & 63;
  float4 v = ((const float4*)(x + (size_t)t * HDIM))[tid];
  float s = v.x + v.y + v.z + v.w;
  float q = v.x * v.x + v.y * v.y + v.z * v.z + v.w * v.w;
#pragma unroll
  for (int mm = 32; mm >= 1; mm >>= 1) {
    s += __shfl_xor(s, mm);
    q += __shfl_xor(q, mm);
  }
  __shared__ float ss[4], qq[4];
  if (lane == 0) { ss[wid] = s; qq[wid] = q; }
  __syncthreads();
  s = ss[0] + ss[1] + ss[2] + ss[3];
  q = qq[0] + qq[1] + qq[2] + qq[3];
  float mu = s * (1.0f / HDIM);
  float var = q * (1.0f / HDIM) - mu * mu;
  float inv = rsqrtf(var + 1e-5f);
  float4 wv = ((const float4*)w)[tid];
  float4 bv = ((const float4*)bias)[tid];
  float y0 = (v.x - mu) * inv * wv.x + bv.x;
  float y1 = (v.y - mu) * inv * wv.y + bv.y;
  float y2 = (v.z - mu) * inv * wv.z + bv.z;
  float y3 = (v.w - mu) * inv * wv.w + bv.w;
  ushort4 h, l;
  split2(y0, h.x, l.x); split2(y1, h.y, l.y);
  split2(y2, h.z, l.z); split2(y3, h.w, l.w);
  if (o2) {
    u16* orow = o2 + (size_t)t * K2 + tid * 4;
    *(ushort4*)(orow) = h;
    *(ushort4*)(orow + 1024) = l;
  }
  if (obf) ((ushort4*)(obf + (size_t)t * HDIM))[tid] = h;
  if (of32) {
    float4 yo; yo.x = y0; yo.y = y1; yo.z = y2; yo.w = y3;
    ((float4*)(of32 + (size_t)t * HDIM))[tid] = yo;
  }
}

// ---- GEMM C[M,N] = A[M,K] * B[N,K]^T, bf16 — R8-proven structure:
//      128x128 tile, BK=64, dbuf, prefetch-next-while-compute, one barrier/step.
// MODE 0/1: [hi|lo] 3-term split with A/B restage-skip.
// MODE 2: moe w1 (grouped, gathered rows) -> gelu -> o0 bf16  [unused this round]
// MODE 3: moe w2 (grouped, contiguous)    -> outf = C * wts
template<int MODE>
__global__ __launch_bounds__(256)
void gemm_bt(const u16* __restrict__ A0, const u16* __restrict__ B0,
             int kstride, int nk, int M,
             const float* __restrict__ resid, float* __restrict__ outf,
             u16* __restrict__ o0, u16* __restrict__ o1, u16* __restrict__ o2,
             u16* __restrict__ o3, u16* __restrict__ o4, u16* __restrict__ o5,
             const int* __restrict__ offs, const int* __restrict__ rowsIdx,
             const float* __restrict__ wts) {
  int tid = threadIdx.x;
  int wid = tid >> 6, lane = tid & 63;
  int l15 = lane & 15, l4 = lane >> 4;
  int slot = tid & 7;
  int bn = blockIdx.x, bm = blockIdx.y, e = blockIdx.z;

  int Me = M, rowBase = 0;
  const u16* A = A0;
  const u16* B = B0;
  if constexpr (MODE == 2 || MODE == 3) {
    int oa = offs[e], ob = offs[e + 1];
    Me = ob - oa; rowBase = oa;
    B = B0 + (size_t)e * (size_t)(MODE == 2 ? FDIM : HDIM) * (size_t)kstride;
    if constexpr (MODE == 3) A = A0 + (size_t)oa * (size_t)kstride;
  }
  if (bm * 128 >= Me) return;

  __shared__ u16 lsA[2][128 * 64];
  __shared__ u16 lsB[2][128 * 64];

  const u16* aPtr[4];
  const u16* bPtr[4];
#pragma unroll
  for (int i = 0; i < 4; i++) {
    int r = i * 32 + (tid >> 3);
    int sl = slot ^ (r & 7);
    int rg = bm * 128 + r;
    if constexpr (MODE == 2) {
      int rc = rg < Me ? rg : (Me - 1);
      rg = rowsIdx[rowBase + rc];
    } else if constexpr (MODE == 3) {
      rg = rg < Me ? rg : (Me - 1);
    }
    aPtr[i] = A + (size_t)rg * kstride + sl * 8;
    bPtr[i] = B + (size_t)(bn * 128 + r) * kstride + sl * 8;
  }

  int wm = (wid >> 1) * 64, wn = (wid & 1) * 64;
  f32x4 zero4 = {0.f, 0.f, 0.f, 0.f};
  f32x4 acc[4][4];
#pragma unroll
  for (int mi = 0; mi < 4; mi++)
#pragma unroll
    for (int ni = 0; ni < 4; ni++) acc[mi][ni] = zero4;

  int aoff[4][2], boff[4][2];
#pragma unroll
  for (int mi = 0; mi < 4; mi++) {
    int row = wm + mi * 16 + l15;
#pragma unroll
    for (int kk = 0; kk < 2; kk++) {
      int cs = kk * 4 + l4;
      aoff[mi][kk] = row * 64 + ((cs ^ (row & 7)) << 3);
    }
  }
#pragma unroll
  for (int ni = 0; ni < 4; ni++) {
    int row = wn + ni * 16 + l15;
#pragma unroll
    for (int kk = 0; kk < 2; kk++) {
      int cs = kk * 4 + l4;
      boff[ni][kk] = row * 64 + ((cs ^ (row & 7)) << 3);
    }
  }

  auto ksched = [&](int s, int& ak, int& bk, bool& stA, bool& stB) {
    if constexpr (MODE <= 1) {
      int kl = s / 3, sub = s - kl * 3;
      ak = (sub == 1 ? 1024 : 0) + kl * 64;
      bk = (sub == 2 ? 1024 : 0) + kl * 64;
      stA = (sub != 2);
      stB = (sub != 1);
    } else {
      ak = s << 6; bk = ak; stA = true; stB = true;
    }
  };

  {
    int ak, bk; bool stA, stB;
    ksched(0, ak, bk, stA, stB);
#pragma unroll
    for (int i = 0; i < 4; i++) {
      int d = (i * 256 + wid * 64) * 8;
      gload_lds16(aPtr[i] + ak, &lsA[0][d]);
      gload_lds16(bPtr[i] + bk, &lsB[0][d]);
    }
  }
  __syncthreads();

  int aBuf = 0, bBuf = 0;
  for (int s = 0; s < nk; ++s) {
    bool flipB = false;
    if (s + 1 < nk) {
      int ak, bk; bool stA, stB;
      ksched(s + 1, ak, bk, stA, stB);
      flipB = stB;
#pragma unroll
      for (int i = 0; i < 4; i++) {
        int d = (i * 256 + wid * 64) * 8;
        if (stA) gload_lds16(aPtr[i] + ak, &lsA[aBuf ^ 1][d]);
        if (stB) gload_lds16(bPtr[i] + bk, &lsB[bBuf ^ 1][d]);
      }
    }
#pragma unroll
    for (int kk = 0; kk < 2; kk++) {
      bf16x8 af[4], bfr[4];
#pragma unroll
      for (int mi = 0; mi < 4; mi++) af[mi] = lds_frag(&lsA[aBuf][aoff[mi][kk]]);
#pragma unroll
      for (int ni = 0; ni < 4; ni++) bfr[ni] = lds_frag(&lsB[bBuf][boff[ni][kk]]);
#pragma unroll
      for (int mi = 0; mi < 4; mi++)
#pragma unroll
        for (int ni = 0; ni < 4; ni++)
          acc[mi][ni] = mfma16(af[mi], bfr[ni], acc[mi][ni]);
    }
    __syncthreads();
    aBuf ^= 1;
    if (flipB) bBuf ^= 1;
  }

#pragma unroll
  for (int mi = 0; mi < 4; mi++) {
#pragma unroll
    for (int r = 0; r < 4; r++) {
      int m = bm * 128 + wm + mi * 16 + l4 * 4 + r;
      if (m >= Me) continue;
#pragma unroll
      for (int ni = 0; ni < 4; ni++) {
        int n = bn * 128 + wn + ni * 16 + l15;
        float v = acc[mi][ni][r];
        if constexpr (MODE == 0) {
          u16 hh, ll; split2(v, hh, ll);
          int sq = m >> 2, bb = m & 3;
          int d = n & 63;
          if (n < 1024) {
            int hd = n >> 6;
            size_t o = ((size_t)(bb * NHEADS + hd) * SLEN + sq) * HD + d;
            o0[o] = hh; o1[o] = ll;
          } else if (n < 1280) {
            int hd = (n - 1024) >> 6;
            size_t o = ((size_t)(bb * NKV + hd) * SLEN + sq) * HD + d;
            o2[o] = hh; o3[o] = ll;
          } else {
            int hd = (n - 1280) >> 6;
            size_t o = ((size_t)(bb * NKV + hd) * SLEN + sq) * HD + d;
            o4[o] = hh; o5[o] = ll;
          }
        } else if constexpr (MODE == 1) {
          size_t iidx = (size_t)m * HDIM + n;
          outf[iidx] = v + resid[iidx];
        } else if constexpr (MODE == 2) {
          float g = 0.5f * v * (1.0f + tanhf(0.7978845608f * (v + 0.044715f * v * v * v)));
          o0[(size_t)(rowBase + m) * FDIM + n] = f2bf(g);
        } else {
          outf[(size_t)(rowBase + m) * HDIM + n] = v * wts[rowBase + m];
        }
      }
    }
  }
}

// ---- MoE w1: BM=256 (2x128 subtiles), BN=128, BK=32, dbuf+prefetch ----
// Same sync structure as gemm_bt (stage-next -> compute -> one barrier).
// Staged bytes/step: 24 KB per 128 block-MFMA (vs 32 KB at 128^2/BK=64).
// LDS 48 KB -> 2 blocks/CU preserved. Swizzle: 32-col half, slot^((row>>1)&3)
// (same involution family refcheck-proven in R9's gemm8).
__global__ __launch_bounds__(256)
void gemm_w1(const u16* __restrict__ A0, const u16* __restrict__ B0,
             int kstride, int nk,
             u16* __restrict__ o0,
             const int* __restrict__ offs, const int* __restrict__ rowsIdx) {
  int tid = threadIdx.x;
  int wid = tid >> 6, lane = tid & 63;
  int l15 = lane & 15, l4 = lane >> 4;
  int bn = blockIdx.x, bm = blockIdx.y, e = blockIdx.z;

  int oa = offs[e], ob = offs[e + 1];
  int Me = ob - oa, rowBase = oa;
  const u16* B = B0 + (size_t)e * (size_t)FDIM * (size_t)kstride;
  if (bm * 256 >= Me) return;

  __shared__ u16 lsA[2][2][128 * 32];
  __shared__ u16 lsB[2][128 * 32];

  // pre-swizzled staging sources: linear chunk s=i*256+tid holds logical
  // 16B slot (s&3)^((row>>1)&3) of row s>>2.
  const u16* aSrc[2][2];
  const u16* bSrc[2];
#pragma unroll
  for (int i = 0; i < 2; i++) {
    int s = i * 256 + tid;
    int r = s >> 2, sl = s & 3;
    int logs = sl ^ ((r >> 1) & 3);
#pragma unroll
    for (int j = 0; j < 2; j++) {
      int rg = bm * 256 + j * 128 + r;
      int rc = rg < Me ? rg : (Me - 1);
      rc = rowsIdx[rowBase + rc];
      aSrc[j][i] = A0 + (size_t)rc * kstride + logs * 8;
    }
    bSrc[i] = B + (size_t)(bn * 128 + r) * kstride + logs * 8;
  }

  int wm = (wid >> 1) * 64, wn = (wid & 1) * 64;
  f32x4 zero4 = {0.f, 0.f, 0.f, 0.f};
  f32x4 acc[2][4][4];
#pragma unroll
  for (int j = 0; j < 2; j++)
#pragma unroll
    for (int mi = 0; mi < 4; mi++)
#pragma unroll
      for (int ni = 0; ni < 4; ni++) acc[j][mi][ni] = zero4;

  int aoff[4], boff[4];
#pragma unroll
  for (int mi = 0; mi < 4; mi++) {
    int row = wm + mi * 16 + l15;
    aoff[mi] = row * 32 + ((l4 ^ ((row >> 1) & 3)) * 8);
  }
#pragma unroll
  for (int ni = 0; ni < 4; ni++) {
    int rn = wn + ni * 16 + l15;
    boff[ni] = rn * 32 + ((l4 ^ ((rn >> 1) & 3)) * 8);
  }

  auto stage = [&](int s, int buf) {
    int k0 = s * 32;
#pragma unroll
    for (int j = 0; j < 2; j++)
#pragma unroll
      for (int i = 0; i < 2; i++)
        gload_lds16(aSrc[j][i] + k0, &lsA[buf][j][(i * 256 + wid * 64) * 8]);
#pragma unroll
    for (int i = 0; i < 2; i++)
      gload_lds16(bSrc[i] + k0, &lsB[buf][(i * 256 + wid * 64) * 8]);
  };

  stage(0, 0);
  __syncthreads();

  int buf = 0;
  for (int s = 0; s < nk; ++s) {
    if (s + 1 < nk) stage(s + 1, buf ^ 1);
    bf16x8 bfr[4];
#pragma unroll
    for (int ni = 0; ni < 4; ni++) bfr[ni] = lds_frag(&lsB[buf][boff[ni]]);
#pragma unroll
    for (int j = 0; j < 2; j++) {
      bf16x8 af[4];
#pragma unroll
      for (int mi = 0; mi < 4; mi++) af[mi] = lds_frag(&lsA[buf][j][aoff[mi]]);
#pragma unroll
      for (int mi = 0; mi < 4; mi++)
#pragma unroll
        for (int ni = 0; ni < 4; ni++)
          acc[j][mi][ni] = mfma16(af[mi], bfr[ni], acc[j][mi][ni]);
    }
    __syncthreads();
    buf ^= 1;
  }

#pragma unroll
  for (int j = 0; j < 2; j++) {
#pragma unroll
    for (int mi = 0; mi < 4; mi++) {
#pragma unroll
      for (int r = 0; r < 4; r++) {
        int m = bm * 256 + j * 128 + wm + mi * 16 + l4 * 4 + r;
        if (m >= Me) continue;
#pragma unroll
        for (int ni = 0; ni < 4; ni++) {
          int n = bn * 128 + wn + ni * 16 + l15;
          float v = acc[j][mi][ni][r];
          float g = 0.5f * v * (1.0f + tanhf(0.7978845608f * (v + 0.044715f * v * v * v)));
          o0[(size_t)(rowBase + m) * FDIM + n] = f2bf(g);
        }
      }
    }
  }
}

// ---- flash attention, causal, GQA, split precision, dbuf-K, prefetch-V ----
__global__ __launch_bounds__(256)
void attn_kernel(const u16* __restrict__ Qh_, const u16* __restrict__ Ql_,
                 const u16* __restrict__ Kh_, const u16* __restrict__ Kl_,
                 const u16* __restrict__ Vh_, const u16* __restrict__ Vl_,
                 u16* __restrict__ A2) {
  int bh = blockIdx.x;
  int qt = blockIdx.y;
  int b = bh >> 4, h = bh & 15, kh = h >> 2;
  int tid = threadIdx.x, wid = tid >> 6, lane = tid & 63;
  int l15 = lane & 15, l4 = lane >> 4;
  int slot = tid & 7;

  size_t qoff = ((size_t)(b * NHEADS + h) * SLEN) * HD;
  size_t koff = ((size_t)(b * NKV + kh) * SLEN) * HD;
  const u16* Qh = Qh_ + qoff;
  const u16* Ql = Ql_ + qoff;
  const u16* Kh = Kh_ + koff;
  const u16* Kl = Kl_ + koff;
  const u16* Vh = Vh_ + koff;
  const u16* Vl = Vl_ + koff;

  __shared__ u16 KtH[2][4096], KtL[2][4096];
  __shared__ u16 VtH[4096], VtL[4096];
  __shared__ u16 PtH[4][1024], PtL[4][1024];

  int qrow = qt * 64 + wid * 16 + l15;
  bf16x8 qfh[2], qfl[2];
#pragma unroll
  for (int kk = 0; kk < 2; kk++) {
    u16x8 vh = *(const u16x8*)(Qh + (size_t)qrow * HD + kk * 32 + l4 * 8);
    u16x8 vl = *(const u16x8*)(Ql + (size_t)qrow * HD + kk * 32 + l4 * 8);
    qfh[kk] = __builtin_bit_cast(bf16x8, vh);
    qfl[kk] = __builtin_bit_cast(bf16x8, vl);
  }

  int kr0 = tid >> 3;
  int kr1 = 32 + (tid >> 3);
  int sl0 = slot ^ (kr0 & 7);
  int sl1 = slot ^ (kr1 & 7);
  int kdst0 = (0 * 256 + wid * 64) * 8;
  int kdst1 = (1 * 256 + wid * 64) * 8;

#define STAGE_K(kt_, bf_)                                                     \
  {                                                                           \
    size_t s0 = (size_t)((kt_)*64 + kr0) * HD + sl0 * 8;                      \
    size_t s1 = (size_t)((kt_)*64 + kr1) * HD + sl1 * 8;                      \
    gload_lds16(Kh + s0, &KtH[bf_][kdst0]);                                   \
    gload_lds16(Kl + s0, &KtL[bf_][kdst0]);                                   \
    gload_lds16(Kh + s1, &KtH[bf_][kdst1]);                                   \
    gload_lds16(Kl + s1, &KtL[bf_][kdst1]);                                   \
  }

#define LOAD_V(kt_, vh_, vl_)                                                 \
  {                                                                           \
    _Pragma("unroll") for (int i = 0; i < 2; i++) {                           \
      int kv = i * 32 + (tid >> 3);                                           \
      (vh_)[i] = *(const uint4*)(Vh + (size_t)((kt_)*64 + kv) * HD + slot * 8);\
      (vl_)[i] = *(const uint4*)(Vl + (size_t)((kt_)*64 + kv) * HD + slot * 8);\
    }                                                                         \
  }

#define SCATTER_V(vh_, vl_)                                                   \
  {                                                                           \
    _Pragma("unroll") for (int i = 0; i < 2; i++) {                           \
      int kv = i * 32 + (tid >> 3);                                           \
      const u16* ph = (const u16*)&(vh_)[i];                                  \
      const u16* pl = (const u16*)&(vl_)[i];                                  \
      _Pragma("unroll") for (int j = 0; j < 8; j++) {                         \
        int d = slot * 8 + j;                                                 \
        int g = ((kv >> 3) ^ (d & 7) ^ (d >> 3)) & 7;                         \
        int addr = d * 64 + (g << 3) + (kv & 7);                              \
        VtH[addr] = ph[j];                                                    \
        VtL[addr] = pl[j];                                                    \
      }                                                                       \
    }                                                                         \
  }

  uint4 vH[2], vL[2];
  STAGE_K(0, 0);
  LOAD_V(0, vH, vL);
  SCATTER_V(vH, vL);
  __syncthreads();

  f32x4 zero4 = {0.f, 0.f, 0.f, 0.f};
  f32x4 oacc[4];
#pragma unroll
  for (int nf = 0; nf < 4; nf++) oacc[nf] = zero4;
  float mrun[4], lrun[4];
#pragma unroll
  for (int r = 0; r < 4; r++) { mrun[r] = -1e30f; lrun[r] = 0.f; }

  int buf = 0;
  for (int kt = 0; kt <= qt; ++kt) {
    int kv0 = kt * 64;
    if (kt < qt) {
      STAGE_K(kt + 1, buf ^ 1);
      LOAD_V(kt + 1, vH, vL);
    }

    f32x4 sacc[4];
#pragma unroll
    for (int nf = 0; nf < 4; nf++) sacc[nf] = zero4;
#pragma unroll
    for (int kk = 0; kk < 2; kk++) {
#pragma unroll
      for (int nf = 0; nf < 4; nf++) {
        int krow = nf * 16 + l15;
        int ka = krow * 64 + (((kk * 4 + l4) ^ (krow & 7)) << 3);
        bf16x8 kfh = lds_frag(&KtH[buf][ka]);
        bf16x8 kfl = lds_frag(&KtL[buf][ka]);
        sacc[nf] = mfma16(qfh[kk], kfh, sacc[nf]);
        sacc[nf] = mfma16(qfh[kk], kfl, sacc[nf]);
        sacc[nf] = mfma16(qfl[kk], kfh, sacc[nf]);
      }
    }

    bool diag = (kt == qt);
    float tm[4];
#pragma unroll
    for (int r = 0; r < 4; r++) tm[r] = -1e30f;
#pragma unroll
    for (int nf = 0; nf < 4; nf++) {
#pragma unroll
      for (int r = 0; r < 4; r++) {
        float s = sacc[nf][r] * 0.125f;
        if (diag) {
          int qg = qt * 64 + wid * 16 + l4 * 4 + r;
          int kg = kv0 + nf * 16 + l15;
          if (kg > qg) s = -1e30f;
        }
        sacc[nf][r] = s;
        tm[r] = fmaxf(tm[r], s);
      }
    }
#pragma unroll
    for (int mm = 1; mm < 16; mm <<= 1) {
#pragma unroll
      for (int r = 0; r < 4; r++) tm[r] = fmaxf(tm[r], __shfl_xor(tm[r], mm));
    }
    float ts[4];
#pragma unroll
    for (int r = 0; r < 4; r++) {
      float mn = fmaxf(mrun[r], tm[r]);
      float al = __expf(mrun[r] - mn);
      mrun[r] = mn;
      lrun[r] *= al;
#pragma unroll
      for (int nf = 0; nf < 4; nf++) oacc[nf][r] *= al;
      ts[r] = 0.f;
    }
#pragma unroll
    for (int nf = 0; nf < 4; nf++) {
#pragma unroll
      for (int r = 0; r < 4; r++) {
        float p = __expf(sacc[nf][r] - mrun[r]);
        sacc[nf][r] = p;
        ts[r] += p;
      }
    }
#pragma unroll
    for (int mm = 1; mm < 16; mm <<= 1) {
#pragma unroll
      for (int r = 0; r < 4; r++) ts[r] += __shfl_xor(ts[r], mm);
    }
#pragma unroll
    for (int r = 0; r < 4; r++) lrun[r] += ts[r];

#pragma unroll
    for (int nf = 0; nf < 4; nf++) {
#pragma unroll
      for (int r = 0; r < 4; r++) {
        int qrl = l4 * 4 + r;
        int kv = nf * 16 + l15;
        int g = ((kv >> 3) ^ (qrl & 7) ^ (qrl >> 3)) & 7;
        int addr = qrl * 64 + (g << 3) + (kv & 7);
        u16 hh, ll;
        split2(sacc[nf][r], hh, ll);
        PtH[wid][addr] = hh;
        PtL[wid][addr] = ll;
      }
    }
#pragma unroll
    for (int s2 = 0; s2 < 2; s2++) {
      int cs = s2 * 4 + l4;
      int pa = l15 * 64 + ((((cs ^ (l15 & 7) ^ (l15 >> 3))) & 7) << 3);
      bf16x8 pfh = lds_frag(&PtH[wid][pa]);
      bf16x8 pfl = lds_frag(&PtL[wid][pa]);
#pragma unroll
      for (int nf = 0; nf < 4; nf++) {
        int d = nf * 16 + l15;
        int va = d * 64 + ((((cs ^ (d & 7) ^ (d >> 3))) & 7) << 3);
        bf16x8 vfh = lds_frag(&VtH[va]);
        bf16x8 vfl = lds_frag(&VtL[va]);
        oacc[nf] = mfma16(pfh, vfh, oacc[nf]);
        oacc[nf] = mfma16(pfh, vfl, oacc[nf]);
        oacc[nf] = mfma16(pfl, vfh, oacc[nf]);
      }
    }

    __syncthreads();
    if (kt < qt) {
      SCATTER_V(vH, vL);
    }
    __syncthreads();
    buf ^= 1;
  }

  // epilogue: attn2 row = [hi | lo]
#pragma unroll
  for (int r = 0; r < 4; r++) {
    float invl = 1.0f / lrun[r];
    int qg = qt * 64 + wid * 16 + l4 * 4 + r;
    size_t tb = ((size_t)qg * BATCH + b) * K2 + h * HD;
#pragma unroll
    for (int nf = 0; nf < 4; nf++) {
      u16 hh, ll;
      split2(oacc[nf][r] * invl, hh, ll);
      size_t o = tb + nf * 16 + l15;
      A2[o] = hh;
      A2[o + 1024] = ll;
    }
  }
#undef STAGE_K
#undef LOAD_V
#undef SCATTER_V
}

// ---- router: logits, softmax, top-2 (no global atomics) ----
__global__ __launch_bounds__(256)
void router_kernel(const float* __restrict__ x, const float* __restrict__ rw,
                   int* __restrict__ tidx, float* __restrict__ tp) {
  int t = blockIdx.x, tid = threadIdx.x;
  int wid = tid >> 6, lane = tid & 63;
  float4 xv = ((const float4*)(x + (size_t)t * HDIM))[tid];
  __shared__ float part[8][4];
  __shared__ float lg[8];
#pragma unroll
  for (int e = 0; e < 8; e++) {
    float4 wv = ((const float4*)(rw + (size_t)e * HDIM))[tid];
    float d = xv.x * wv.x + xv.y * wv.y + xv.z * wv.z + xv.w * wv.w;
#pragma unroll
    for (int mm = 32; mm >= 1; mm >>= 1) d += __shfl_xor(d, mm);
    if (lane == 0) part[e][wid] = d;
  }
  __syncthreads();
  if (tid < 8) lg[tid] = part[tid][0] + part[tid][1] + part[tid][2] + part[tid][3];
  __syncthreads();
  if (tid == 0) {
    float mx = lg[0];
#pragma unroll
    for (int e = 1; e < 8; e++) mx = fmaxf(mx, lg[e]);
    float g[8]; float se = 0.f;
#pragma unroll
    for (int e = 0; e < 8; e++) { g[e] = __expf(lg[e] - mx); se += g[e]; }
    float inv = 1.0f / se;
#pragma unroll
    for (int e = 0; e < 8; e++) g[e] *= inv;
    int i0 = 0; float v0 = g[0];
#pragma unroll
    for (int e = 1; e < 8; e++) if (g[e] > v0) { v0 = g[e]; i0 = e; }
    int i1 = -1; float v1 = -1.f;
#pragma unroll
    for (int e = 0; e < 8; e++) if (e != i0 && g[e] > v1) { v1 = g[e]; i1 = e; }
    tidx[t * 2] = i0; tidx[t * 2 + 1] = i1;
    tp[t * 2] = v0; tp[t * 2 + 1] = v1;
  }
}

// ---- histogram (expert x rep) + offsets + repBase; zero curRep. One block. ----
__global__ __launch_bounds__(256)
void hist_offsets_kernel(const int* __restrict__ tidx, int* __restrict__ offs,
                         int* __restrict__ repBase, int* __restrict__ curRep) {
  __shared__ int hist[NEXP * NREP];
  __shared__ int eoffs[NEXP + 1];
  int tid = threadIdx.x;
  hist[tid] = 0;
  __syncthreads();
  for (int i = tid; i < TTOK; i += 256) {
    int rep = i & (NREP - 1);
    atomicAdd(&hist[tidx[2 * i] * NREP + rep], 1);
    atomicAdd(&hist[tidx[2 * i + 1] * NREP + rep], 1);
  }
  __syncthreads();
  if (tid == 0) {
    int a = 0;
    for (int e = 0; e < NEXP; e++) {
      eoffs[e] = a;
      for (int r = 0; r < NREP; r++) a += hist[e * NREP + r];
    }
    eoffs[NEXP] = a;
  }
  __syncthreads();
  if (tid < NEXP) {
    int a = eoffs[tid];
    for (int r = 0; r < NREP; r++) {
      repBase[tid * NREP + r] = a;
      a += hist[tid * NREP + r];
    }
  }
  if (tid < NEXP + 1) offs[tid] = eoffs[tid];
  curRep[tid] = 0;
}

// ---- assign: atomics spread over NEXP*NREP counters ----
__global__ __launch_bounds__(256)
void assign_kernel(const int* __restrict__ tidx, const float* __restrict__ tp,
                   const int* __restrict__ repBase, int* __restrict__ curRep,
                   int* __restrict__ rowsIdx, float* __restrict__ wvals,
                   int* __restrict__ inv) {
  int t = blockIdx.x * blockDim.x + threadIdx.x;
  if (t >= TTOK) return;
  int rep = t & (NREP - 1);
#pragma unroll
  for (int k = 0; k < 2; k++) {
    int e = tidx[t * 2 + k];
    int s = atomicAdd(&curRep[e * NREP + rep], 1);
    int pos = repBase[e * NREP + rep] + s;
    rowsIdx[pos] = t;
    wvals[pos] = tp[t * 2 + k];
    inv[t * 2 + k] = pos;
  }
}

__global__ __launch_bounds__(256)
void combine_kernel(float* __restrict__ out, const float* __restrict__ eo,
                    const int* __restrict__ inv) {
  int t = blockIdx.x, c = threadIdx.x;
  int r0 = inv[t * 2], r1 = inv[t * 2 + 1];
  float4* o = (float4*)(out + (size_t)t * HDIM);
  const float4* e0 = (const float4*)(eo + (size_t)r0 * HDIM);
  const float4* e1 = (const float4*)(eo + (size_t)r1 * HDIM);
  float4 v = o[c];
  float4 a = e0[c];
  float4 bb = e1[c];
  v.x += a.x + bb.x; v.y += a.y + bb.y; v.z += a.z + bb.z; v.w += a.w + bb.w;
  o[c] = v;
}

extern "C" void kernel_launch(void* const* d_in, const int* in_sizes, int n_in,
                              void* d_out, int out_size, void* d_ws, size_t ws_size,
                              hipStream_t stream) {
  (void)in_sizes; (void)n_in; (void)out_size; (void)ws_size;
  const float* hs    = (const float*)d_in[0];
  const float* ln1w  = (const float*)d_in[1];
  const float* ln1b  = (const float*)d_in[2];
  const float* ln2w  = (const float*)d_in[3];
  const float* ln2b  = (const float*)d_in[4];
  const float* wqkv  = (const float*)d_in[5];
  const float* wproj = (const float*)d_in[6];
  const float* wrout = (const float*)d_in[7];
  const float* w1    = (const float*)d_in[8];
  const float* w2    = (const float*)d_in[9];
  float* out = (float*)d_out;

  char* base = (char*)d_ws;
  size_t off = 0;
  auto alloc = [&](size_t n) { void* r = base + off; off += (n + 255) & ~(size_t)255; return r; };

  const size_t SZ_W1T   = (size_t)NEXP * FDIM * HDIM * 2;
  const size_t SZ_W2T   = (size_t)NEXP * HDIM * FDIM * 2;
  const size_t SZ_WP2   = (size_t)HDIM * K2 * 2;
  const size_t SZ_LN12  = (size_t)TTOK * K2 * 2;
  const size_t SZ_WQ2   = (size_t)QKVO * K2 * 2;
  const size_t SZ_HMID  = (size_t)TTOK * 2 * FDIM * 2;
  const size_t SZ_Q     = (size_t)BATCH * NHEADS * SLEN * HD * 2;
  const size_t SZ_KV    = (size_t)BATCH * NKV * SLEN * HD * 2;
  const size_t SZ_A2    = (size_t)TTOK * K2 * 2;
  const size_t SZ_EO    = (size_t)TTOK * 2 * HDIM * 4;

  u16* w1t     = (u16*)alloc(SZ_W1T);
  u16* w2t     = (u16*)alloc(SZ_W2T);
  u16* wproj2  = (u16*)alloc(SZ_WP2);

  size_t r1sz = SZ_LN12 + SZ_WQ2;
  if (SZ_HMID > r1sz) r1sz = SZ_HMID;
  char* r1 = (char*)alloc(r1sz);
  u16* ln1_2 = (u16*)r1;
  u16* wqkv2 = (u16*)(r1 + SZ_LN12);
  u16* hmid  = (u16*)r1;

  size_t r2sz = 2 * SZ_Q + 4 * SZ_KV + SZ_A2;
  if (SZ_EO > r2sz) r2sz = SZ_EO;
  char* r2 = (char*)alloc(r2sz);
  u16* Qbh = (u16*)r2;
  u16* Qbl = (u16*)(r2 + SZ_Q);
  u16* Kbh = (u16*)(r2 + 2 * SZ_Q);
  u16* Kbl = (u16*)(r2 + 2 * SZ_Q + SZ_KV);
  u16* Vbh = (u16*)(r2 + 2 * SZ_Q + 2 * SZ_KV);
  u16* Vbl = (u16*)(r2 + 2 * SZ_Q + 3 * SZ_KV);
  u16* attn2 = (u16*)(r2 + 2 * SZ_Q + 4 * SZ_KV);
  float* eo = (float*)r2;

  u16* ln2o    = (u16*)alloc((size_t)TTOK * HDIM * 2);
  float* ln2f  = (float*)alloc((size_t)TTOK * HDIM * 4);
  int* tidx    = (int*)alloc(TTOK * 2 * 4);
  float* tp    = (float*)alloc(TTOK * 2 * 4);
  int* rowsIdx = (int*)alloc(TTOK * 2 * 4);
  float* wvals = (float*)alloc(TTOK * 2 * 4);
  int* invm    = (int*)alloc(TTOK * 2 * 4);
  int* offs    = (int*)alloc((NEXP + 1) * 4);
  int* repBase = (int*)alloc(NEXP * NREP * 4);
  int* curRep  = (int*)alloc(NEXP * NREP * 4);

  // weight prep
  cvt_w2_kernel<<<(QKVO * HDIM / 4 + 255) / 256, 256, 0, stream>>>(wqkv, wqkv2, QKVO * HDIM / 4);
  cvt_w2_kernel<<<(HDIM * HDIM / 4 + 255) / 256, 256, 0, stream>>>(wproj, wproj2, HDIM * HDIM / 4);
  dim3 tb(32, 8);
  transpose_cvt_kernel<<<dim3(FDIM / 32, HDIM / 32, NEXP), tb, 0, stream>>>(w1, w1t, HDIM, FDIM);
  transpose_cvt_kernel<<<dim3(HDIM / 32, FDIM / 32, NEXP), tb, 0, stream>>>(w2, w2t, FDIM, HDIM);

  ln_kernel<<<TTOK, 256, 0, stream>>>(hs, ln1w, ln1b, ln1_2, nullptr, nullptr);

  // QKV: 3-term K-schedule (48 steps over [hi|lo] 2048, A/B restage-skip)
  gemm_bt<0><<<dim3(QKVO / 128, TTOK / 128), 256, 0, stream>>>(
      ln1_2, wqkv2, K2, 48, TTOK, nullptr, nullptr,
      Qbh, Qbl, Kbh, Kbl, Vbh, Vbl, nullptr, nullptr, nullptr);

  attn_kernel<<<dim3(BATCH * NHEADS, SLEN / 64), 256, 0, stream>>>(
      Qbh, Qbl, Kbh, Kbl, Vbh, Vbl, attn2);

  gemm_bt<1><<<dim3(HDIM / 128, TTOK / 128), 256, 0, stream>>>(
      attn2, wproj2, K2, 48, TTOK, hs, out,
      nullptr, nullptr, nullptr, nullptr, nullptr, nullptr, nullptr, nullptr, nullptr);

  ln_kernel<<<TTOK, 256, 0, stream>>>(out, ln2w, ln2b, nullptr, ln2o, ln2f);

  router_kernel<<<TTOK, 256, 0, stream>>>(ln2f, wrout, tidx, tp);
  hist_offsets_kernel<<<1, 256, 0, stream>>>(tidx, offs, repBase, curRep);
  assign_kernel<<<TTOK / 256, 256, 0, stream>>>(tidx, tp, repBase, curRep, rowsIdx, wvals, invm);

  // MoE w1: BM=256 two-subtile, BK=32 (staged-bytes -25%, 2 blocks/CU)
  gemm_w1<<<dim3(FDIM / 128, TTOK / 256, NEXP), 256, 0, stream>>>(
      ln2o, w1t, HDIM, HDIM / 32, hmid, offs, rowsIdx);

  // MoE w2: R8-proven 128^2 dbuf-prefetch
  gemm_bt<3><<<dim3(HDIM / 128, TTOK / 128, NEXP), 256, 0, stream>>>(
      hmid, w2t, FDIM, 32, 0, nullptr, eo,
      nullptr, nullptr, nullptr, nullptr, nullptr, nullptr, offs, nullptr, wvals);

  combine_kernel<<<TTOK, 256, 0, stream>>>(out, eo, invm);
}

// Round 11
// 466.308 us; speedup vs baseline: 1.1045x; 1.1045x over previous
//
#include <hip/hip_runtime.h>
#include <stdint.h>

typedef unsigned short u16;
typedef float f32x4 __attribute__((ext_vector_type(4)));
typedef __bf16 bf16x8 __attribute__((ext_vector_type(8)));
typedef u16 u16x8 __attribute__((ext_vector_type(8)));

#define NHEADS 16
#define NKV 4
#define HD 64
#define HDIM 1024
#define FDIM 2048
#define SLEN 1024
#define BATCH 4
#define TTOK 4096
#define NEXP 8
#define QKVO 1536
#define K2 2048
#define NREP 32

__device__ __forceinline__ u16 f2bf(float f) {
  union { float f; uint32_t u; } c; c.f = f;
  uint32_t u = c.u;
  return (u16)((u + 0x7FFFu + ((u >> 16) & 1u)) >> 16);
}
__device__ __forceinline__ float bf2f(u16 h) {
  union { uint32_t u; float f; } c; c.u = ((uint32_t)h) << 16; return c.f;
}
__device__ __forceinline__ void split2(float v, u16& h, u16& l) {
  h = f2bf(v);
  l = f2bf(v - bf2f(h));
}

__device__ __forceinline__ f32x4 mfma16(bf16x8 a, bf16x8 b, f32x4 c) {
  return __builtin_amdgcn_mfma_f32_16x16x32_bf16(a, b, c, 0, 0, 0);
}

__device__ __forceinline__ bf16x8 lds_frag(const u16* base) {
  u16x8 v = *(const u16x8*)base;
  return __builtin_bit_cast(bf16x8, v);
}

__device__ __forceinline__ void gload_lds16(const void* g, void* l) {
  __builtin_amdgcn_global_load_lds((const __attribute__((address_space(1))) void*)g,
                                   (__attribute__((address_space(3))) void*)l, 16, 0, 0);
}

// ---- fp32 weight [R][1024] -> split bf16 [R][2048] = [hi|lo] ----
__global__ __launch_bounds__(256)
void cvt_w2_kernel(const float* __restrict__ in, u16* __restrict__ out, int n4) {
  int i = blockIdx.x * blockDim.x + threadIdx.x;
  if (i >= n4) return;
  float4 v = ((const float4*)in)[i];
  int row = i >> 8;
  int c = (i & 255) * 4;
  ushort4 h, l;
  split2(v.x, h.x, l.x); split2(v.y, h.y, l.y);
  split2(v.z, h.z, l.z); split2(v.w, h.w, l.w);
  u16* orow = out + (size_t)row * K2 + c;
  *(ushort4*)(orow) = h;
  *(ushort4*)(orow + 1024) = l;
}

// ---- tiled transpose + convert: in [R][C] f32 -> out [C][R] bf16, z = expert ----
__global__ __launch_bounds__(256)
void transpose_cvt_kernel(const float* __restrict__ in, u16* __restrict__ out, int R, int C) {
  __shared__ float tile[32][33];
  size_t eoff = (size_t)blockIdx.z * (size_t)R * (size_t)C;
  in += eoff; out += eoff;
  int c0 = blockIdx.x * 32, r0 = blockIdx.y * 32;
  int tx = threadIdx.x, ty = threadIdx.y;
#pragma unroll
  for (int i = 0; i < 4; i++)
    tile[ty + i * 8][tx] = in[(size_t)(r0 + ty + i * 8) * C + c0 + tx];
  __syncthreads();
#pragma unroll
  for (int i = 0; i < 4; i++)
    out[(size_t)(c0 + ty + i * 8) * R + r0 + tx] = f2bf(tile[tx][ty + i * 8]);
}

// ---- LayerNorm: o2 ([hi|lo] 2048-wide) OR (obf single + of32) ----
__global__ __launch_bounds__(256)
void ln_kernel(const float* __restrict__ x, const float* __restrict__ w,
               const float* __restrict__ bias, u16* __restrict__ o2,
               u16* __restrict__ obf, float* __restrict__ of32) {
  int t = blockIdx.x, tid = threadIdx.x;
  int wid = tid >> 6, lane = tid & 63;
  float4 v = ((const float4*)(x + (size_t)t * HDIM))[tid];
  float s = v.x + v.y + v.z + v.w;
  float q = v.x * v.x + v.y * v.y + v.z * v.z + v.w * v.w;
#pragma unroll
  for (int mm = 32; mm >= 1; mm >>= 1) {
    s += __shfl_xor(s, mm);
    q += __shfl_xor(q, mm);
  }
  __shared__ float ss[4], qq[4];
  if (lane == 0) { ss[wid] = s; qq[wid] = q; }
  __syncthreads();
  s = ss[0] + ss[1] + ss[2] + ss[3];
  q = qq[0] + qq[1] + qq[2] + qq[3];
  float mu = s * (1.0f / HDIM);
  float var = q * (1.0f / HDIM) - mu * mu;
  float inv = rsqrtf(var + 1e-5f);
  float4 wv = ((const float4*)w)[tid];
  float4 bv = ((const float4*)bias)[tid];
  float y0 = (v.x - mu) * inv * wv.x + bv.x;
  float y1 = (v.y - mu) * inv * wv.y + bv.y;
  float y2 = (v.z - mu) * inv * wv.z + bv.z;
  float y3 = (v.w - mu) * inv * wv.w + bv.w;
  ushort4 h, l;
  split2(y0, h.x, l.x); split2(y1, h.y, l.y);
  split2(y2, h.z, l.z); split2(y3, h.w, l.w);
  if (o2) {
    u16* orow = o2 + (size_t)t * K2 + tid * 4;
    *(ushort4*)(orow) = h;
    *(ushort4*)(orow + 1024) = l;
  }
  if (obf) ((ushort4*)(obf + (size_t)t * HDIM))[tid] = h;
  if (of32) {
    float4 yo; yo.x = y0; yo.y = y1; yo.z = y2; yo.w = y3;
    ((float4*)(of32 + (size_t)t * HDIM))[tid] = yo;
  }
}

// ---- GEMM C[M,N] = A[M,K] * B[N,K]^T, bf16 — R8-proven structure:
//      128x128 tile, BK=64, dbuf, prefetch-next-while-compute, one barrier/step.
//      NO setprio (R7: scheduler fence, 2.6x slowdown). NO XCD swizzle.
// MODE 0/1: [hi|lo] 3-term split with A/B restage-skip (4 staged tiles / 3 steps).
// MODE 2: moe w1 (grouped, gathered rows) -> gelu -> o0 bf16
// MODE 3: moe w2 (grouped, contiguous)    -> outf = C * wts
template<int MODE>
__global__ __launch_bounds__(256)
void gemm_bt(const u16* __restrict__ A0, const u16* __restrict__ B0,
             int kstride, int nk, int M,
             const float* __restrict__ resid, float* __restrict__ outf,
             u16* __restrict__ o0, u16* __restrict__ o1, u16* __restrict__ o2,
             u16* __restrict__ o3, u16* __restrict__ o4, u16* __restrict__ o5,
             const int* __restrict__ offs, const int* __restrict__ rowsIdx,
             const float* __restrict__ wts) {
  int tid = threadIdx.x;
  int wid = tid >> 6, lane = tid & 63;
  int l15 = lane & 15, l4 = lane >> 4;
  int slot = tid & 7;
  int bn = blockIdx.x, bm = blockIdx.y, e = blockIdx.z;

  int Me = M, rowBase = 0;
  const u16* A = A0;
  const u16* B = B0;
  if constexpr (MODE == 2 || MODE == 3) {
    int oa = offs[e], ob = offs[e + 1];
    Me = ob - oa; rowBase = oa;
    B = B0 + (size_t)e * (size_t)(MODE == 2 ? FDIM : HDIM) * (size_t)kstride;
    if constexpr (MODE == 3) A = A0 + (size_t)oa * (size_t)kstride;
  }
  if (bm * 128 >= Me) return;

  __shared__ u16 lsA[2][128 * 64];
  __shared__ u16 lsB[2][128 * 64];

  const u16* aPtr[4];
  const u16* bPtr[4];
#pragma unroll
  for (int i = 0; i < 4; i++) {
    int r = i * 32 + (tid >> 3);
    int sl = slot ^ (r & 7);
    int rg = bm * 128 + r;
    if constexpr (MODE == 2) {
      int rc = rg < Me ? rg : (Me - 1);
      rg = rowsIdx[rowBase + rc];
    } else if constexpr (MODE == 3) {
      rg = rg < Me ? rg : (Me - 1);
    }
    aPtr[i] = A + (size_t)rg * kstride + sl * 8;
    bPtr[i] = B + (size_t)(bn * 128 + r) * kstride + sl * 8;
  }

  int wm = (wid >> 1) * 64, wn = (wid & 1) * 64;
  f32x4 zero4 = {0.f, 0.f, 0.f, 0.f};
  f32x4 acc[4][4];
#pragma unroll
  for (int mi = 0; mi < 4; mi++)
#pragma unroll
    for (int ni = 0; ni < 4; ni++) acc[mi][ni] = zero4;

  int aoff[4][2], boff[4][2];
#pragma unroll
  for (int mi = 0; mi < 4; mi++) {
    int row = wm + mi * 16 + l15;
#pragma unroll
    for (int kk = 0; kk < 2; kk++) {
      int cs = kk * 4 + l4;
      aoff[mi][kk] = row * 64 + ((cs ^ (row & 7)) << 3);
    }
  }
#pragma unroll
  for (int ni = 0; ni < 4; ni++) {
    int row = wn + ni * 16 + l15;
#pragma unroll
    for (int kk = 0; kk < 2; kk++) {
      int cs = kk * 4 + l4;
      boff[ni][kk] = row * 64 + ((cs ^ (row & 7)) << 3);
    }
  }

  auto ksched = [&](int s, int& ak, int& bk, bool& stA, bool& stB) {
    if constexpr (MODE <= 1) {
      int kl = s / 3, sub = s - kl * 3;
      ak = (sub == 1 ? 1024 : 0) + kl * 64;
      bk = (sub == 2 ? 1024 : 0) + kl * 64;
      stA = (sub != 2);
      stB = (sub != 1);
    } else {
      ak = s << 6; bk = ak; stA = true; stB = true;
    }
  };

  {
    int ak, bk; bool stA, stB;
    ksched(0, ak, bk, stA, stB);
#pragma unroll
    for (int i = 0; i < 4; i++) {
      int d = (i * 256 + wid * 64) * 8;
      gload_lds16(aPtr[i] + ak, &lsA[0][d]);
      gload_lds16(bPtr[i] + bk, &lsB[0][d]);
    }
  }
  __syncthreads();

  int aBuf = 0, bBuf = 0;
  for (int s = 0; s < nk; ++s) {
    bool flipB = false;
    if (s + 1 < nk) {
      int ak, bk; bool stA, stB;
      ksched(s + 1, ak, bk, stA, stB);
      flipB = stB;
#pragma unroll
      for (int i = 0; i < 4; i++) {
        int d = (i * 256 + wid * 64) * 8;
        if (stA) gload_lds16(aPtr[i] + ak, &lsA[aBuf ^ 1][d]);
        if (stB) gload_lds16(bPtr[i] + bk, &lsB[bBuf ^ 1][d]);
      }
    }
#pragma unroll
    for (int kk = 0; kk < 2; kk++) {
      bf16x8 af[4], bfr[4];
#pragma unroll
      for (int mi = 0; mi < 4; mi++) af[mi] = lds_frag(&lsA[aBuf][aoff[mi][kk]]);
#pragma unroll
      for (int ni = 0; ni < 4; ni++) bfr[ni] = lds_frag(&lsB[bBuf][boff[ni][kk]]);
#pragma unroll
      for (int mi = 0; mi < 4; mi++)
#pragma unroll
        for (int ni = 0; ni < 4; ni++)
          acc[mi][ni] = mfma16(af[mi], bfr[ni], acc[mi][ni]);
    }
    __syncthreads();
    aBuf ^= 1;
    if (flipB) bBuf ^= 1;
  }

#pragma unroll
  for (int mi = 0; mi < 4; mi++) {
#pragma unroll
    for (int r = 0; r < 4; r++) {
      int m = bm * 128 + wm + mi * 16 + l4 * 4 + r;
      if (m >= Me) continue;
#pragma unroll
      for (int ni = 0; ni < 4; ni++) {
        int n = bn * 128 + wn + ni * 16 + l15;
        float v = acc[mi][ni][r];
        if constexpr (MODE == 0) {
          u16 hh, ll; split2(v, hh, ll);
          int sq = m >> 2, bb = m & 3;
          int d = n & 63;
          if (n < 1024) {
            int hd = n >> 6;
            size_t o = ((size_t)(bb * NHEADS + hd) * SLEN + sq) * HD + d;
            o0[o] = hh; o1[o] = ll;
          } else if (n < 1280) {
            int hd = (n - 1024) >> 6;
            size_t o = ((size_t)(bb * NKV + hd) * SLEN + sq) * HD + d;
            o2[o] = hh; o3[o] = ll;
          } else {
            int hd = (n - 1280) >> 6;
            size_t o = ((size_t)(bb * NKV + hd) * SLEN + sq) * HD + d;
            o4[o] = hh; o5[o] = ll;
          }
        } else if constexpr (MODE == 1) {
          size_t iidx = (size_t)m * HDIM + n;
          outf[iidx] = v + resid[iidx];
        } else if constexpr (MODE == 2) {
          float g = 0.5f * v * (1.0f + tanhf(0.7978845608f * (v + 0.044715f * v * v * v)));
          o0[(size_t)(rowBase + m) * FDIM + n] = f2bf(g);
        } else {
          outf[(size_t)(rowBase + m) * HDIM + n] = v * wts[rowBase + m];
        }
      }
    }
  }
}

// ---- flash attention, causal, GQA, split precision, dbuf-K, prefetch-V ----
__global__ __launch_bounds__(256)
void attn_kernel(const u16* __restrict__ Qh_, const u16* __restrict__ Ql_,
                 const u16* __restrict__ Kh_, const u16* __restrict__ Kl_,
                 const u16* __restrict__ Vh_, const u16* __restrict__ Vl_,
                 u16* __restrict__ A2) {
  int bh = blockIdx.x;
  int qt = blockIdx.y;
  int b = bh >> 4, h = bh & 15, kh = h >> 2;
  int tid = threadIdx.x, wid = tid >> 6, lane = tid & 63;
  int l15 = lane & 15, l4 = lane >> 4;
  int slot = tid & 7;

  size_t qoff = ((size_t)(b * NHEADS + h) * SLEN) * HD;
  size_t koff = ((size_t)(b * NKV + kh) * SLEN) * HD;
  const u16* Qh = Qh_ + qoff;
  const u16* Ql = Ql_ + qoff;
  const u16* Kh = Kh_ + koff;
  const u16* Kl = Kl_ + koff;
  const u16* Vh = Vh_ + koff;
  const u16* Vl = Vl_ + koff;

  __shared__ u16 KtH[2][4096], KtL[2][4096];
  __shared__ u16 VtH[4096], VtL[4096];
  __shared__ u16 PtH[4][1024], PtL[4][1024];

  int qrow = qt * 64 + wid * 16 + l15;
  bf16x8 qfh[2], qfl[2];
#pragma unroll
  for (int kk = 0; kk < 2; kk++) {
    u16x8 vh = *(const u16x8*)(Qh + (size_t)qrow * HD + kk * 32 + l4 * 8);
    u16x8 vl = *(const u16x8*)(Ql + (size_t)qrow * HD + kk * 32 + l4 * 8);
    qfh[kk] = __builtin_bit_cast(bf16x8, vh);
    qfl[kk] = __builtin_bit_cast(bf16x8, vl);
  }

  int kr0 = tid >> 3;
  int kr1 = 32 + (tid >> 3);
  int sl0 = slot ^ (kr0 & 7);
  int sl1 = slot ^ (kr1 & 7);
  int kdst0 = (0 * 256 + wid * 64) * 8;
  int kdst1 = (1 * 256 + wid * 64) * 8;

#define STAGE_K(kt_, bf_)                                                     \
  {                                                                           \
    size_t s0 = (size_t)((kt_)*64 + kr0) * HD + sl0 * 8;                      \
    size_t s1 = (size_t)((kt_)*64 + kr1) * HD + sl1 * 8;                      \
    gload_lds16(Kh + s0, &KtH[bf_][kdst0]);                                   \
    gload_lds16(Kl + s0, &KtL[bf_][kdst0]);                                   \
    gload_lds16(Kh + s1, &KtH[bf_][kdst1]);                                   \
    gload_lds16(Kl + s1, &KtL[bf_][kdst1]);                                   \
  }

#define LOAD_V(kt_, vh_, vl_)                                                 \
  {                                                                           \
    _Pragma("unroll") for (int i = 0; i < 2; i++) {                           \
      int kv = i * 32 + (tid >> 3);                                           \
      (vh_)[i] = *(const uint4*)(Vh + (size_t)((kt_)*64 + kv) * HD + slot * 8);\
      (vl_)[i] = *(const uint4*)(Vl + (size_t)((kt_)*64 + kv) * HD + slot * 8);\
    }                                                                         \
  }

#define SCATTER_V(vh_, vl_)                                                   \
  {                                                                           \
    _Pragma("unroll") for (int i = 0; i < 2; i++) {                           \
      int kv = i * 32 + (tid >> 3);                                           \
      const u16* ph = (const u16*)&(vh_)[i];                                  \
      const u16* pl = (const u16*)&(vl_)[i];                                  \
      _Pragma("unroll") for (int j = 0; j < 8; j++) {                         \
        int d = slot * 8 + j;                                                 \
        int g = ((kv >> 3) ^ (d & 7) ^ (d >> 3)) & 7;                         \
        int addr = d * 64 + (g << 3) + (kv & 7);                              \
        VtH[addr] = ph[j];                                                    \
        VtL[addr] = pl[j];                                                    \
      }                                                                       \
    }                                                                         \
  }

  uint4 vH[2], vL[2];
  STAGE_K(0, 0);
  LOAD_V(0, vH, vL);
  SCATTER_V(vH, vL);
  __syncthreads();

  f32x4 zero4 = {0.f, 0.f, 0.f, 0.f};
  f32x4 oacc[4];
#pragma unroll
  for (int nf = 0; nf < 4; nf++) oacc[nf] = zero4;
  float mrun[4], lrun[4];
#pragma unroll
  for (int r = 0; r < 4; r++) { mrun[r] = -1e30f; lrun[r] = 0.f; }

  int buf = 0;
  for (int kt = 0; kt <= qt; ++kt) {
    int kv0 = kt * 64;
    if (kt < qt) {
      STAGE_K(kt + 1, buf ^ 1);
      LOAD_V(kt + 1, vH, vL);
    }

    f32x4 sacc[4];
#pragma unroll
    for (int nf = 0; nf < 4; nf++) sacc[nf] = zero4;
#pragma unroll
    for (int kk = 0; kk < 2; kk++) {
#pragma unroll
      for (int nf = 0; nf < 4; nf++) {
        int krow = nf * 16 + l15;
        int ka = krow * 64 + (((kk * 4 + l4) ^ (krow & 7)) << 3);
        bf16x8 kfh = lds_frag(&KtH[buf][ka]);
        bf16x8 kfl = lds_frag(&KtL[buf][ka]);
        sacc[nf] = mfma16(qfh[kk], kfh, sacc[nf]);
        sacc[nf] = mfma16(qfh[kk], kfl, sacc[nf]);
        sacc[nf] = mfma16(qfl[kk], kfh, sacc[nf]);
      }
    }

    bool diag = (kt == qt);
    float tm[4];
#pragma unroll
    for (int r = 0; r < 4; r++) tm[r] = -1e30f;
#pragma unroll
    for (int nf = 0; nf < 4; nf++) {
#pragma unroll
      for (int r = 0; r < 4; r++) {
        float s = sacc[nf][r] * 0.125f;
        if (diag) {
          int qg = qt * 64 + wid * 16 + l4 * 4 + r;
          int kg = kv0 + nf * 16 + l15;
          if (kg > qg) s = -1e30f;
        }
        sacc[nf][r] = s;
        tm[r] = fmaxf(tm[r], s);
      }
    }
#pragma unroll
    for (int mm = 1; mm < 16; mm <<= 1) {
#pragma unroll
      for (int r = 0; r < 4; r++) tm[r] = fmaxf(tm[r], __shfl_xor(tm[r], mm));
    }
    float ts[4];
#pragma unroll
    for (int r = 0; r < 4; r++) {
      float mn = fmaxf(mrun[r], tm[r]);
      float al = __expf(mrun[r] - mn);
      mrun[r] = mn;
      lrun[r] *= al;
#pragma unroll
      for (int nf = 0; nf < 4; nf++) oacc[nf][r] *= al;
      ts[r] = 0.f;
    }
#pragma unroll
    for (int nf = 0; nf < 4; nf++) {
#pragma unroll
      for (int r = 0; r < 4; r++) {
        float p = __expf(sacc[nf][r] - mrun[r]);
        sacc[nf][r] = p;
        ts[r] += p;
      }
    }
#pragma unroll
    for (int mm = 1; mm < 16; mm <<= 1) {
#pragma unroll
      for (int r = 0; r < 4; r++) ts[r] += __shfl_xor(ts[r], mm);
    }
#pragma unroll
    for (int r = 0; r < 4; r++) lrun[r] += ts[r];

#pragma unroll
    for (int nf = 0; nf < 4; nf++) {
#pragma unroll
      for (int r = 0; r < 4; r++) {
        int qrl = l4 * 4 + r;
        int kv = nf * 16 + l15;
        int g = ((kv >> 3) ^ (qrl & 7) ^ (qrl >> 3)) & 7;
        int addr = qrl * 64 + (g << 3) + (kv & 7);
        u16 hh, ll;
        split2(sacc[nf][r], hh, ll);
        PtH[wid][addr] = hh;
        PtL[wid][addr] = ll;
      }
    }
#pragma unroll
    for (int s2 = 0; s2 < 2; s2++) {
      int cs = s2 * 4 + l4;
      int pa = l15 * 64 + ((((cs ^ (l15 & 7) ^ (l15 >> 3))) & 7) << 3);
      bf16x8 pfh = lds_frag(&PtH[wid][pa]);
      bf16x8 pfl = lds_frag(&PtL[wid][pa]);
#pragma unroll
      for (int nf = 0; nf < 4; nf++) {
        int d = nf * 16 + l15;
        int va = d * 64 + ((((cs ^ (d & 7) ^ (d >> 3))) & 7) << 3);
        bf16x8 vfh = lds_frag(&VtH[va]);
        bf16x8 vfl = lds_frag(&VtL[va]);
        oacc[nf] = mfma16(pfh, vfh, oacc[nf]);
        oacc[nf] = mfma16(pfh, vfl, oacc[nf]);
        oacc[nf] = mfma16(pfl, vfh, oacc[nf]);
      }
    }

    __syncthreads();
    if (kt < qt) {
      SCATTER_V(vH, vL);
    }
    __syncthreads();
    buf ^= 1;
  }

  // epilogue: attn2 row = [hi | lo]
#pragma unroll
  for (int r = 0; r < 4; r++) {
    float invl = 1.0f / lrun[r];
    int qg = qt * 64 + wid * 16 + l4 * 4 + r;
    size_t tb = ((size_t)qg * BATCH + b) * K2 + h * HD;
#pragma unroll
    for (int nf = 0; nf < 4; nf++) {
      u16 hh, ll;
      split2(oacc[nf][r] * invl, hh, ll);
      size_t o = tb + nf * 16 + l15;
      A2[o] = hh;
      A2[o + 1024] = ll;
    }
  }
#undef STAGE_K
#undef LOAD_V
#undef SCATTER_V
}

// ---- router: logits, softmax, top-2 (no global atomics) ----
__global__ __launch_bounds__(256)
void router_kernel(const float* __restrict__ x, const float* __restrict__ rw,
                   int* __restrict__ tidx, float* __restrict__ tp) {
  int t = blockIdx.x, tid = threadIdx.x;
  int wid = tid >> 6, lane = tid & 63;
  float4 xv = ((const float4*)(x + (size_t)t * HDIM))[tid];
  __shared__ float part[8][4];
  __shared__ float lg[8];
#pragma unroll
  for (int e = 0; e < 8; e++) {
    float4 wv = ((const float4*)(rw + (size_t)e * HDIM))[tid];
    float d = xv.x * wv.x + xv.y * wv.y + xv.z * wv.z + xv.w * wv.w;
#pragma unroll
    for (int mm = 32; mm >= 1; mm >>= 1) d += __shfl_xor(d, mm);
    if (lane == 0) part[e][wid] = d;
  }
  __syncthreads();
  if (tid < 8) lg[tid] = part[tid][0] + part[tid][1] + part[tid][2] + part[tid][3];
  __syncthreads();
  if (tid == 0) {
    float mx = lg[0];
#pragma unroll
    for (int e = 1; e < 8; e++) mx = fmaxf(mx, lg[e]);
    float g[8]; float se = 0.f;
#pragma unroll
    for (int e = 0; e < 8; e++) { g[e] = __expf(lg[e] - mx); se += g[e]; }
    float inv = 1.0f / se;
#pragma unroll
    for (int e = 0; e < 8; e++) g[e] *= inv;
    int i0 = 0; float v0 = g[0];
#pragma unroll
    for (int e = 1; e < 8; e++) if (g[e] > v0) { v0 = g[e]; i0 = e; }
    int i1 = -1; float v1 = -1.f;
#pragma unroll
    for (int e = 0; e < 8; e++) if (e != i0 && g[e] > v1) { v1 = g[e]; i1 = e; }
    tidx[t * 2] = i0; tidx[t * 2 + 1] = i1;
    tp[t * 2] = v0; tp[t * 2 + 1] = v1;
  }
}

// ---- histogram (expert x rep) + offsets + repBase; zero curRep. One block. ----
__global__ __launch_bounds__(256)
void hist_offsets_kernel(const int* __restrict__ tidx, int* __restrict__ offs,
                         int* __restrict__ repBase, int* __restrict__ curRep) {
  __shared__ int hist[NEXP * NREP];
  __shared__ int eoffs[NEXP + 1];
  int tid = threadIdx.x;
  hist[tid] = 0;
  __syncthreads();
  for (int i = tid; i < TTOK; i += 256) {
    int rep = i & (NREP - 1);
    atomicAdd(&hist[tidx[2 * i] * NREP + rep], 1);
    atomicAdd(&hist[tidx[2 * i + 1] * NREP + rep], 1);
  }
  __syncthreads();
  if (tid == 0) {
    int a = 0;
    for (int e = 0; e < NEXP; e++) {
      eoffs[e] = a;
      for (int r = 0; r < NREP; r++) a += hist[e * NREP + r];
    }
    eoffs[NEXP] = a;
  }
  __syncthreads();
  if (tid < NEXP) {
    int a = eoffs[tid];
    for (int r = 0; r < NREP; r++) {
      repBase[tid * NREP + r] = a;
      a += hist[tid * NREP + r];
    }
  }
  if (tid < NEXP + 1) offs[tid] = eoffs[tid];
  curRep[tid] = 0;
}

// ---- assign: atomics spread over NEXP*NREP counters ----
__global__ __launch_bounds__(256)
void assign_kernel(const int* __restrict__ tidx, const float* __restrict__ tp,
                   const int* __restrict__ repBase, int* __restrict__ curRep,
                   int* __restrict__ rowsIdx, float* __restrict__ wvals,
                   int* __restrict__ inv) {
  int t = blockIdx.x * blockDim.x + threadIdx.x;
  if (t >= TTOK) return;
  int rep = t & (NREP - 1);
#pragma unroll
  for (int k = 0; k < 2; k++) {
    int e = tidx[t * 2 + k];
    int s = atomicAdd(&curRep[e * NREP + rep], 1);
    int pos = repBase[e * NREP + rep] + s;
    rowsIdx[pos] = t;
    wvals[pos] = tp[t * 2 + k];
    inv[t * 2 + k] = pos;
  }
}

__global__ __launch_bounds__(256)
void combine_kernel(float* __restrict__ out, const float* __restrict__ eo,
                    const int* __restrict__ inv) {
  int t = blockIdx.x, c = threadIdx.x;
  int r0 = inv[t * 2], r1 = inv[t * 2 + 1];
  float4* o = (float4*)(out + (size_t)t * HDIM);
  const float4* e0 = (const float4*)(eo + (size_t)r0 * HDIM);
  const float4* e1 = (const float4*)(eo + (size_t)r1 * HDIM);
  float4 v = o[c];
  float4 a = e0[c];
  float4 bb = e1[c];
  v.x += a.x + bb.x; v.y += a.y + bb.y; v.z += a.z + bb.z; v.w += a.w + bb.w;
  o[c] = v;
}

extern "C" void kernel_launch(void* const* d_in, const int* in_sizes, int n_in,
                              void* d_out, int out_size, void* d_ws, size_t ws_size,
                              hipStream_t stream) {
  (void)in_sizes; (void)n_in; (void)out_size; (void)ws_size;
  const float* hs    = (const float*)d_in[0];
  const float* ln1w  = (const float*)d_in[1];
  const float* ln1b  = (const float*)d_in[2];
  const float* ln2w  = (const float*)d_in[3];
  const float* ln2b  = (const float*)d_in[4];
  const float* wqkv  = (const float*)d_in[5];
  const float* wproj = (const float*)d_in[6];
  const float* wrout = (const float*)d_in[7];
  const float* w1    = (const float*)d_in[8];
  const float* w2    = (const float*)d_in[9];
  float* out = (float*)d_out;

  char* base = (char*)d_ws;
  size_t off = 0;
  auto alloc = [&](size_t n) { void* r = base + off; off += (n + 255) & ~(size_t)255; return r; };

  const size_t SZ_W1T   = (size_t)NEXP * FDIM * HDIM * 2;
  const size_t SZ_W2T   = (size_t)NEXP * HDIM * FDIM * 2;
  const size_t SZ_WP2   = (size_t)HDIM * K2 * 2;
  const size_t SZ_LN12  = (size_t)TTOK * K2 * 2;
  const size_t SZ_WQ2   = (size_t)QKVO * K2 * 2;
  const size_t SZ_HMID  = (size_t)TTOK * 2 * FDIM * 2;
  const size_t SZ_Q     = (size_t)BATCH * NHEADS * SLEN * HD * 2;
  const size_t SZ_KV    = (size_t)BATCH * NKV * SLEN * HD * 2;
  const size_t SZ_A2    = (size_t)TTOK * K2 * 2;
  const size_t SZ_EO    = (size_t)TTOK * 2 * HDIM * 4;

  u16* w1t     = (u16*)alloc(SZ_W1T);
  u16* w2t     = (u16*)alloc(SZ_W2T);
  u16* wproj2  = (u16*)alloc(SZ_WP2);

  size_t r1sz = SZ_LN12 + SZ_WQ2;
  if (SZ_HMID > r1sz) r1sz = SZ_HMID;
  char* r1 = (char*)alloc(r1sz);
  u16* ln1_2 = (u16*)r1;
  u16* wqkv2 = (u16*)(r1 + SZ_LN12);
  u16* hmid  = (u16*)r1;

  size_t r2sz = 2 * SZ_Q + 4 * SZ_KV + SZ_A2;
  if (SZ_EO > r2sz) r2sz = SZ_EO;
  char* r2 = (char*)alloc(r2sz);
  u16* Qbh = (u16*)r2;
  u16* Qbl = (u16*)(r2 + SZ_Q);
  u16* Kbh = (u16*)(r2 + 2 * SZ_Q);
  u16* Kbl = (u16*)(r2 + 2 * SZ_Q + SZ_KV);
  u16* Vbh = (u16*)(r2 + 2 * SZ_Q + 2 * SZ_KV);
  u16* Vbl = (u16*)(r2 + 2 * SZ_Q + 3 * SZ_KV);
  u16* attn2 = (u16*)(r2 + 2 * SZ_Q + 4 * SZ_KV);
  float* eo = (float*)r2;

  u16* ln2o    = (u16*)alloc((size_t)TTOK * HDIM * 2);
  float* ln2f  = (float*)alloc((size_t)TTOK * HDIM * 4);
  int* tidx    = (int*)alloc(TTOK * 2 * 4);
  float* tp    = (float*)alloc(TTOK * 2 * 4);
  int* rowsIdx = (int*)alloc(TTOK * 2 * 4);
  float* wvals = (float*)alloc(TTOK * 2 * 4);
  int* invm    = (int*)alloc(TTOK * 2 * 4);
  int* offs    = (int*)alloc((NEXP + 1) * 4);
  int* repBase = (int*)alloc(NEXP * NREP * 4);
  int* curRep  = (int*)alloc(NEXP * NREP * 4);

  // weight prep
  cvt_w2_kernel<<<(QKVO * HDIM / 4 + 255) / 256, 256, 0, stream>>>(wqkv, wqkv2, QKVO * HDIM / 4);
  cvt_w2_kernel<<<(HDIM * HDIM / 4 + 255) / 256, 256, 0, stream>>>(wproj, wproj2, HDIM * HDIM / 4);
  dim3 tb(32, 8);
  transpose_cvt_kernel<<<dim3(FDIM / 32, HDIM / 32, NEXP), tb, 0, stream>>>(w1, w1t, HDIM, FDIM);
  transpose_cvt_kernel<<<dim3(HDIM / 32, FDIM / 32, NEXP), tb, 0, stream>>>(w2, w2t, FDIM, HDIM);

  ln_kernel<<<TTOK, 256, 0, stream>>>(hs, ln1w, ln1b, ln1_2, nullptr, nullptr);

  // QKV: 3-term K-schedule (48 steps over [hi|lo] 2048, A/B restage-skip)
  gemm_bt<0><<<dim3(QKVO / 128, TTOK / 128), 256, 0, stream>>>(
      ln1_2, wqkv2, K2, 48, TTOK, nullptr, nullptr,
      Qbh, Qbl, Kbh, Kbl, Vbh, Vbl, nullptr, nullptr, nullptr);

  attn_kernel<<<dim3(BATCH * NHEADS, SLEN / 64), 256, 0, stream>>>(
      Qbh, Qbl, Kbh, Kbl, Vbh, Vbl, attn2);

  gemm_bt<1><<<dim3(HDIM / 128, TTOK / 128), 256, 0, stream>>>(
      attn2, wproj2, K2, 48, TTOK, hs, out,
      nullptr, nullptr, nullptr, nullptr, nullptr, nullptr, nullptr, nullptr, nullptr);

  ln_kernel<<<TTOK, 256, 0, stream>>>(out, ln2w, ln2b, nullptr, ln2o, ln2f);

  router_kernel<<<TTOK, 256, 0, stream>>>(ln2f, wrout, tidx, tp);
  hist_offsets_kernel<<<1, 256, 0, stream>>>(tidx, offs, repBase, curRep);
  assign_kernel<<<TTOK / 256, 256, 0, stream>>>(tidx, tp, repBase, curRep, rowsIdx, wvals, invm);

  gemm_bt<2><<<dim3(FDIM / 128, TTOK / 128, NEXP), 256, 0, stream>>>(
      ln2o, w1t, HDIM, 16, 0, nullptr, nullptr,
      hmid, nullptr, nullptr, nullptr, nullptr, nullptr, offs, rowsIdx, nullptr);

  gemm_bt<3><<<dim3(HDIM / 128, TTOK / 128, NEXP), 256, 0, stream>>>(
      hmid, w2t, FDIM, 32, 0, nullptr, eo,
      nullptr, nullptr, nullptr, nullptr, nullptr, nullptr, offs, nullptr, wvals);

  combine_kernel<<<TTOK, 256, 0, stream>>>(out, eo, invm);
}

// Round 12
// 453.689 us; speedup vs baseline: 1.1353x; 1.0278x over previous
//
#include <hip/hip_runtime.h>
#include <stdint.h>

typedef unsigned short u16;
typedef float f32x4 __attribute__((ext_vector_type(4)));
typedef __bf16 bf16x8 __attribute__((ext_vector_type(8)));
typedef u16 u16x8 __attribute__((ext_vector_type(8)));

#define NHEADS 16
#define NKV 4
#define HD 64
#define HDIM 1024
#define FDIM 2048
#define SLEN 1024
#define BATCH 4
#define TTOK 4096
#define NEXP 8
#define QKVO 1536
#define K2 2048
#define NREP 32

__device__ __forceinline__ u16 f2bf(float f) {
  union { float f; uint32_t u; } c; c.f = f;
  uint32_t u = c.u;
  return (u16)((u + 0x7FFFu + ((u >> 16) & 1u)) >> 16);
}
__device__ __forceinline__ float bf2f(u16 h) {
  union { uint32_t u; float f; } c; c.u = ((uint32_t)h) << 16; return c.f;
}
__device__ __forceinline__ void split2(float v, u16& h, u16& l) {
  h = f2bf(v);
  l = f2bf(v - bf2f(h));
}

__device__ __forceinline__ f32x4 mfma16(bf16x8 a, bf16x8 b, f32x4 c) {
  return __builtin_amdgcn_mfma_f32_16x16x32_bf16(a, b, c, 0, 0, 0);
}

__device__ __forceinline__ bf16x8 lds_frag(const u16* base) {
  u16x8 v = *(const u16x8*)base;
  return __builtin_bit_cast(bf16x8, v);
}

__device__ __forceinline__ void gload_lds16(const void* g, void* l) {
  __builtin_amdgcn_global_load_lds((const __attribute__((address_space(1))) void*)g,
                                   (__attribute__((address_space(3))) void*)l, 16, 0, 0);
}

// ---- fp32 weight [R][1024] -> split bf16 [R][2048] = [hi|lo] ----
__global__ __launch_bounds__(256)
void cvt_w2_kernel(const float* __restrict__ in, u16* __restrict__ out, int n4) {
  int i = blockIdx.x * blockDim.x + threadIdx.x;
  if (i >= n4) return;
  float4 v = ((const float4*)in)[i];
  int row = i >> 8;
  int c = (i & 255) * 4;
  ushort4 h, l;
  split2(v.x, h.x, l.x); split2(v.y, h.y, l.y);
  split2(v.z, h.z, l.z); split2(v.w, h.w, l.w);
  u16* orow = out + (size_t)row * K2 + c;
  *(ushort4*)(orow) = h;
  *(ushort4*)(orow + 1024) = l;
}

// ---- tiled transpose + convert: in [R][C] f32 -> out [C][R] bf16, z = expert ----
__global__ __launch_bounds__(256)
void transpose_cvt_kernel(const float* __restrict__ in, u16* __restrict__ out, int R, int C) {
  __shared__ float tile[32][33];
  size_t eoff = (size_t)blockIdx.z * (size_t)R * (size_t)C;
  in += eoff; out += eoff;
  int c0 = blockIdx.x * 32, r0 = blockIdx.y * 32;
  int tx = threadIdx.x, ty = threadIdx.y;
#pragma unroll
  for (int i = 0; i < 4; i++)
    tile[ty + i * 8][tx] = in[(size_t)(r0 + ty + i * 8) * C + c0 + tx];
  __syncthreads();
#pragma unroll
  for (int i = 0; i < 4; i++)
    out[(size_t)(c0 + ty + i * 8) * R + r0 + tx] = f2bf(tile[tx][ty + i * 8]);
}

// ---- LayerNorm: o2 ([hi|lo] 2048-wide) OR (obf single + of32) ----
__global__ __launch_bounds__(256)
void ln_kernel(const float* __restrict__ x, const float* __restrict__ w,
               const float* __restrict__ bias, u16* __restrict__ o2,
               u16* __restrict__ obf, float* __restrict__ of32) {
  int t = blockIdx.x, tid = threadIdx.x;
  int wid = tid >> 6, lane = tid & 63;
  float4 v = ((const float4*)(x + (size_t)t * HDIM))[tid];
  float s = v.x + v.y + v.z + v.w;
  float q = v.x * v.x + v.y * v.y + v.z * v.z + v.w * v.w;
#pragma unroll
  for (int mm = 32; mm >= 1; mm >>= 1) {
    s += __shfl_xor(s, mm);
    q += __shfl_xor(q, mm);
  }
  __shared__ float ss[4], qq[4];
  if (lane == 0) { ss[wid] = s; qq[wid] = q; }
  __syncthreads();
  s = ss[0] + ss[1] + ss[2] + ss[3];
  q = qq[0] + qq[1] + qq[2] + qq[3];
  float mu = s * (1.0f / HDIM);
  float var = q * (1.0f / HDIM) - mu * mu;
  float inv = rsqrtf(var + 1e-5f);
  float4 wv = ((const float4*)w)[tid];
  float4 bv = ((const float4*)bias)[tid];
  float y0 = (v.x - mu) * inv * wv.x + bv.x;
  float y1 = (v.y - mu) * inv * wv.y + bv.y;
  float y2 = (v.z - mu) * inv * wv.z + bv.z;
  float y3 = (v.w - mu) * inv * wv.w + bv.w;
  ushort4 h, l;
  split2(y0, h.x, l.x); split2(y1, h.y, l.y);
  split2(y2, h.z, l.z); split2(y3, h.w, l.w);
  if (o2) {
    u16* orow = o2 + (size_t)t * K2 + tid * 4;
    *(ushort4*)(orow) = h;
    *(ushort4*)(orow + 1024) = l;
  }
  if (obf) ((ushort4*)(obf + (size_t)t * HDIM))[tid] = h;
  if (of32) {
    float4 yo; yo.x = y0; yo.y = y1; yo.z = y2; yo.w = y3;
    ((float4*)(of32 + (size_t)t * HDIM))[tid] = yo;
  }
}

// ---- GEMM C[M,N] = A[M,K] * B[N,K]^T, bf16 — R8-proven structure:
//      128x128 tile, BK=64, dbuf, prefetch-next-while-compute, one barrier/step.
//      NO setprio. Locality block->XCD remap (dispatch round-robin: flat%8=XCD):
//      MODE 0/1: bm-group pinned per XCD (A panels L2-hot across bn sweep)
//      MODE 2/3: expert pinned per XCD (4MB B panel L2-resident)
// MODE 0/1: [hi|lo] 3-term split with A/B restage-skip.
// MODE 2: moe w1 (grouped, gathered rows) -> gelu -> o0 bf16
// MODE 3: moe w2 (grouped, contiguous)    -> outf = C * wts
template<int MODE>
__global__ __launch_bounds__(256)
void gemm_bt(const u16* __restrict__ A0, const u16* __restrict__ B0,
             int kstride, int nk, int M,
             const float* __restrict__ resid, float* __restrict__ outf,
             u16* __restrict__ o0, u16* __restrict__ o1, u16* __restrict__ o2,
             u16* __restrict__ o3, u16* __restrict__ o4, u16* __restrict__ o5,
             const int* __restrict__ offs, const int* __restrict__ rowsIdx,
             const float* __restrict__ wts) {
  int tid = threadIdx.x;
  int wid = tid >> 6, lane = tid & 63;
  int l15 = lane & 15, l4 = lane >> 4;
  int slot = tid & 7;

  int gx = gridDim.x, gy = gridDim.y;
  int bn, bm, e;
  if constexpr (MODE <= 1) {
    // gy == 32 (divisible by 8). Same-bm blocks land on the same XCD.
    int flat = blockIdx.y * gx + blockIdx.x;
    int grp = flat & 7;
    int idx = flat >> 3;          // < gx * gy/8
    bn = idx % gx;
    bm = grp + 8 * (idx / gx);    // < gy
    e = 0;
  } else {
    // Same-expert blocks land on the same XCD (B panel 4MB ~ one L2).
    int flat = (blockIdx.z * gy + blockIdx.y) * gx + blockIdx.x;
    e = flat & 7;
    int idx = flat >> 3;          // < gx * gy
    bn = idx % gx;
    bm = idx / gx;                // < gy
  }

  int Me = M, rowBase = 0;
  const u16* A = A0;
  const u16* B = B0;
  if constexpr (MODE == 2 || MODE == 3) {
    int oa = offs[e], ob = offs[e + 1];
    Me = ob - oa; rowBase = oa;
    B = B0 + (size_t)e * (size_t)(MODE == 2 ? FDIM : HDIM) * (size_t)kstride;
    if constexpr (MODE == 3) A = A0 + (size_t)oa * (size_t)kstride;
  }
  if (bm * 128 >= Me) return;

  __shared__ u16 lsA[2][128 * 64];
  __shared__ u16 lsB[2][128 * 64];

  const u16* aPtr[4];
  const u16* bPtr[4];
#pragma unroll
  for (int i = 0; i < 4; i++) {
    int r = i * 32 + (tid >> 3);
    int sl = slot ^ (r & 7);
    int rg = bm * 128 + r;
    if constexpr (MODE == 2) {
      int rc = rg < Me ? rg : (Me - 1);
      rg = rowsIdx[rowBase + rc];
    } else if constexpr (MODE == 3) {
      rg = rg < Me ? rg : (Me - 1);
    }
    aPtr[i] = A + (size_t)rg * kstride + sl * 8;
    bPtr[i] = B + (size_t)(bn * 128 + r) * kstride + sl * 8;
  }

  int wm = (wid >> 1) * 64, wn = (wid & 1) * 64;
  f32x4 zero4 = {0.f, 0.f, 0.f, 0.f};
  f32x4 acc[4][4];
#pragma unroll
  for (int mi = 0; mi < 4; mi++)
#pragma unroll
    for (int ni = 0; ni < 4; ni++) acc[mi][ni] = zero4;

  int aoff[4][2], boff[4][2];
#pragma unroll
  for (int mi = 0; mi < 4; mi++) {
    int row = wm + mi * 16 + l15;
#pragma unroll
    for (int kk = 0; kk < 2; kk++) {
      int cs = kk * 4 + l4;
      aoff[mi][kk] = row * 64 + ((cs ^ (row & 7)) << 3);
    }
  }
#pragma unroll
  for (int ni = 0; ni < 4; ni++) {
    int row = wn + ni * 16 + l15;
#pragma unroll
    for (int kk = 0; kk < 2; kk++) {
      int cs = kk * 4 + l4;
      boff[ni][kk] = row * 64 + ((cs ^ (row & 7)) << 3);
    }
  }

  auto ksched = [&](int s, int& ak, int& bk, bool& stA, bool& stB) {
    if constexpr (MODE <= 1) {
      int kl = s / 3, sub = s - kl * 3;
      ak = (sub == 1 ? 1024 : 0) + kl * 64;
      bk = (sub == 2 ? 1024 : 0) + kl * 64;
      stA = (sub != 2);
      stB = (sub != 1);
    } else {
      ak = s << 6; bk = ak; stA = true; stB = true;
    }
  };

  {
    int ak, bk; bool stA, stB;
    ksched(0, ak, bk, stA, stB);
#pragma unroll
    for (int i = 0; i < 4; i++) {
      int d = (i * 256 + wid * 64) * 8;
      gload_lds16(aPtr[i] + ak, &lsA[0][d]);
      gload_lds16(bPtr[i] + bk, &lsB[0][d]);
    }
  }
  __syncthreads();

  int aBuf = 0, bBuf = 0;
  for (int s = 0; s < nk; ++s) {
    bool flipB = false;
    if (s + 1 < nk) {
      int ak, bk; bool stA, stB;
      ksched(s + 1, ak, bk, stA, stB);
      flipB = stB;
#pragma unroll
      for (int i = 0; i < 4; i++) {
        int d = (i * 256 + wid * 64) * 8;
        if (stA) gload_lds16(aPtr[i] + ak, &lsA[aBuf ^ 1][d]);
        if (stB) gload_lds16(bPtr[i] + bk, &lsB[bBuf ^ 1][d]);
      }
    }
#pragma unroll
    for (int kk = 0; kk < 2; kk++) {
      bf16x8 af[4], bfr[4];
#pragma unroll
      for (int mi = 0; mi < 4; mi++) af[mi] = lds_frag(&lsA[aBuf][aoff[mi][kk]]);
#pragma unroll
      for (int ni = 0; ni < 4; ni++) bfr[ni] = lds_frag(&lsB[bBuf][boff[ni][kk]]);
#pragma unroll
      for (int mi = 0; mi < 4; mi++)
#pragma unroll
        for (int ni = 0; ni < 4; ni++)
          acc[mi][ni] = mfma16(af[mi], bfr[ni], acc[mi][ni]);
    }
    __syncthreads();
    aBuf ^= 1;
    if (flipB) bBuf ^= 1;
  }

#pragma unroll
  for (int mi = 0; mi < 4; mi++) {
#pragma unroll
    for (int r = 0; r < 4; r++) {
      int m = bm * 128 + wm + mi * 16 + l4 * 4 + r;
      if (m >= Me) continue;
#pragma unroll
      for (int ni = 0; ni < 4; ni++) {
        int n = bn * 128 + wn + ni * 16 + l15;
        float v = acc[mi][ni][r];
        if constexpr (MODE == 0) {
          u16 hh, ll; split2(v, hh, ll);
          int sq = m >> 2, bb = m & 3;
          int d = n & 63;
          if (n < 1024) {
            int hd = n >> 6;
            size_t o = ((size_t)(bb * NHEADS + hd) * SLEN + sq) * HD + d;
            o0[o] = hh; o1[o] = ll;
          } else if (n < 1280) {
            int hd = (n - 1024) >> 6;
            size_t o = ((size_t)(bb * NKV + hd) * SLEN + sq) * HD + d;
            o2[o] = hh; o3[o] = ll;
          } else {
            int hd = (n - 1280) >> 6;
            size_t o = ((size_t)(bb * NKV + hd) * SLEN + sq) * HD + d;
            o4[o] = hh; o5[o] = ll;
          }
        } else if constexpr (MODE == 1) {
          size_t iidx = (size_t)m * HDIM + n;
          outf[iidx] = v + resid[iidx];
        } else if constexpr (MODE == 2) {
          float g = 0.5f * v * (1.0f + tanhf(0.7978845608f * (v + 0.044715f * v * v * v)));
          o0[(size_t)(rowBase + m) * FDIM + n] = f2bf(g);
        } else {
          outf[(size_t)(rowBase + m) * HDIM + n] = v * wts[rowBase + m];
        }
      }
    }
  }
}

// ---- flash attention, causal, GQA, split precision, dbuf-K, prefetch-V ----
__global__ __launch_bounds__(256)
void attn_kernel(const u16* __restrict__ Qh_, const u16* __restrict__ Ql_,
                 const u16* __restrict__ Kh_, const u16* __restrict__ Kl_,
                 const u16* __restrict__ Vh_, const u16* __restrict__ Vl_,
                 u16* __restrict__ A2) {
  int bh = blockIdx.x;
  int qt = blockIdx.y;
  int b = bh >> 4, h = bh & 15, kh = h >> 2;
  int tid = threadIdx.x, wid = tid >> 6, lane = tid & 63;
  int l15 = lane & 15, l4 = lane >> 4;
  int slot = tid & 7;

  size_t qoff = ((size_t)(b * NHEADS + h) * SLEN) * HD;
  size_t koff = ((size_t)(b * NKV + kh) * SLEN) * HD;
  const u16* Qh = Qh_ + qoff;
  const u16* Ql = Ql_ + qoff;
  const u16* Kh = Kh_ + koff;
  const u16* Kl = Kl_ + koff;
  const u16* Vh = Vh_ + koff;
  const u16* Vl = Vl_ + koff;

  __shared__ u16 KtH[2][4096], KtL[2][4096];
  __shared__ u16 VtH[4096], VtL[4096];
  __shared__ u16 PtH[4][1024], PtL[4][1024];

  int qrow = qt * 64 + wid * 16 + l15;
  bf16x8 qfh[2], qfl[2];
#pragma unroll
  for (int kk = 0; kk < 2; kk++) {
    u16x8 vh = *(const u16x8*)(Qh + (size_t)qrow * HD + kk * 32 + l4 * 8);
    u16x8 vl = *(const u16x8*)(Ql + (size_t)qrow * HD + kk * 32 + l4 * 8);
    qfh[kk] = __builtin_bit_cast(bf16x8, vh);
    qfl[kk] = __builtin_bit_cast(bf16x8, vl);
  }

  int kr0 = tid >> 3;
  int kr1 = 32 + (tid >> 3);
  int sl0 = slot ^ (kr0 & 7);
  int sl1 = slot ^ (kr1 & 7);
  int kdst0 = (0 * 256 + wid * 64) * 8;
  int kdst1 = (1 * 256 + wid * 64) * 8;

#define STAGE_K(kt_, bf_)                                                     \
  {                                                                           \
    size_t s0 = (size_t)((kt_)*64 + kr0) * HD + sl0 * 8;                      \
    size_t s1 = (size_t)((kt_)*64 + kr1) * HD + sl1 * 8;                      \
    gload_lds16(Kh + s0, &KtH[bf_][kdst0]);                                   \
    gload_lds16(Kl + s0, &KtL[bf_][kdst0]);                                   \
    gload_lds16(Kh + s1, &KtH[bf_][kdst1]);                                   \
    gload_lds16(Kl + s1, &KtL[bf_][kdst1]);                                   \
  }

#define LOAD_V(kt_, vh_, vl_)                                                 \
  {                                                                           \
    _Pragma("unroll") for (int i = 0; i < 2; i++) {                           \
      int kv = i * 32 + (tid >> 3);                                           \
      (vh_)[i] = *(const uint4*)(Vh + (size_t)((kt_)*64 + kv) * HD + slot * 8);\
      (vl_)[i] = *(const uint4*)(Vl + (size_t)((kt_)*64 + kv) * HD + slot * 8);\
    }                                                                         \
  }

#define SCATTER_V(vh_, vl_)                                                   \
  {                                                                           \
    _Pragma("unroll") for (int i = 0; i < 2; i++) {                           \
      int kv = i * 32 + (tid >> 3);                                           \
      const u16* ph = (const u16*)&(vh_)[i];                                  \
      const u16* pl = (const u16*)&(vl_)[i];                                  \
      _Pragma("unroll") for (int j = 0; j < 8; j++) {                         \
        int d = slot * 8 + j;                                                 \
        int g = ((kv >> 3) ^ (d & 7) ^ (d >> 3)) & 7;                         \
        int addr = d * 64 + (g << 3) + (kv & 7);                              \
        VtH[addr] = ph[j];                                                    \
        VtL[addr] = pl[j];                                                    \
      }                                                                       \
    }                                                                         \
  }

  uint4 vH[2], vL[2];
  STAGE_K(0, 0);
  LOAD_V(0, vH, vL);
  SCATTER_V(vH, vL);
  __syncthreads();

  f32x4 zero4 = {0.f, 0.f, 0.f, 0.f};
  f32x4 oacc[4];
#pragma unroll
  for (int nf = 0; nf < 4; nf++) oacc[nf] = zero4;
  float mrun[4], lrun[4];
#pragma unroll
  for (int r = 0; r < 4; r++) { mrun[r] = -1e30f; lrun[r] = 0.f; }

  int buf = 0;
  for (int kt = 0; kt <= qt; ++kt) {
    int kv0 = kt * 64;
    if (kt < qt) {
      STAGE_K(kt + 1, buf ^ 1);
      LOAD_V(kt + 1, vH, vL);
    }

    f32x4 sacc[4];
#pragma unroll
    for (int nf = 0; nf < 4; nf++) sacc[nf] = zero4;
#pragma unroll
    for (int kk = 0; kk < 2; kk++) {
#pragma unroll
      for (int nf = 0; nf < 4; nf++) {
        int krow = nf * 16 + l15;
        int ka = krow * 64 + (((kk * 4 + l4) ^ (krow & 7)) << 3);
        bf16x8 kfh = lds_frag(&KtH[buf][ka]);
        bf16x8 kfl = lds_frag(&KtL[buf][ka]);
        sacc[nf] = mfma16(qfh[kk], kfh, sacc[nf]);
        sacc[nf] = mfma16(qfh[kk], kfl, sacc[nf]);
        sacc[nf] = mfma16(qfl[kk], kfh, sacc[nf]);
      }
    }

    bool diag = (kt == qt);
    float tm[4];
#pragma unroll
    for (int r = 0; r < 4; r++) tm[r] = -1e30f;
#pragma unroll
    for (int nf = 0; nf < 4; nf++) {
#pragma unroll
      for (int r = 0; r < 4; r++) {
        float s = sacc[nf][r] * 0.125f;
        if (diag) {
          int qg = qt * 64 + wid * 16 + l4 * 4 + r;
          int kg = kv0 + nf * 16 + l15;
          if (kg > qg) s = -1e30f;
        }
        sacc[nf][r] = s;
        tm[r] = fmaxf(tm[r], s);
      }
    }
#pragma unroll
    for (int mm = 1; mm < 16; mm <<= 1) {
#pragma unroll
      for (int r = 0; r < 4; r++) tm[r] = fmaxf(tm[r], __shfl_xor(tm[r], mm));
    }
    float ts[4];
#pragma unroll
    for (int r = 0; r < 4; r++) {
      float mn = fmaxf(mrun[r], tm[r]);
      float al = __expf(mrun[r] - mn);
      mrun[r] = mn;
      lrun[r] *= al;
#pragma unroll
      for (int nf = 0; nf < 4; nf++) oacc[nf][r] *= al;
      ts[r] = 0.f;
    }
#pragma unroll
    for (int nf = 0; nf < 4; nf++) {
#pragma unroll
      for (int r = 0; r < 4; r++) {
        float p = __expf(sacc[nf][r] - mrun[r]);
        sacc[nf][r] = p;
        ts[r] += p;
      }
    }
#pragma unroll
    for (int mm = 1; mm < 16; mm <<= 1) {
#pragma unroll
      for (int r = 0; r < 4; r++) ts[r] += __shfl_xor(ts[r], mm);
    }
#pragma unroll
    for (int r = 0; r < 4; r++) lrun[r] += ts[r];

#pragma unroll
    for (int nf = 0; nf < 4; nf++) {
#pragma unroll
      for (int r = 0; r < 4; r++) {
        int qrl = l4 * 4 + r;
        int kv = nf * 16 + l15;
        int g = ((kv >> 3) ^ (qrl & 7) ^ (qrl >> 3)) & 7;
        int addr = qrl * 64 + (g << 3) + (kv & 7);
        u16 hh, ll;
        split2(sacc[nf][r], hh, ll);
        PtH[wid][addr] = hh;
        PtL[wid][addr] = ll;
      }
    }
#pragma unroll
    for (int s2 = 0; s2 < 2; s2++) {
      int cs = s2 * 4 + l4;
      int pa = l15 * 64 + ((((cs ^ (l15 & 7) ^ (l15 >> 3))) & 7) << 3);
      bf16x8 pfh = lds_frag(&PtH[wid][pa]);
      bf16x8 pfl = lds_frag(&PtL[wid][pa]);
#pragma unroll
      for (int nf = 0; nf < 4; nf++) {
        int d = nf * 16 + l15;
        int va = d * 64 + ((((cs ^ (d & 7) ^ (d >> 3))) & 7) << 3);
        bf16x8 vfh = lds_frag(&VtH[va]);
        bf16x8 vfl = lds_frag(&VtL[va]);
        oacc[nf] = mfma16(pfh, vfh, oacc[nf]);
        oacc[nf] = mfma16(pfh, vfl, oacc[nf]);
        oacc[nf] = mfma16(pfl, vfh, oacc[nf]);
      }
    }

    __syncthreads();
    if (kt < qt) {
      SCATTER_V(vH, vL);
    }
    __syncthreads();
    buf ^= 1;
  }

  // epilogue: attn2 row = [hi | lo]
#pragma unroll
  for (int r = 0; r < 4; r++) {
    float invl = 1.0f / lrun[r];
    int qg = qt * 64 + wid * 16 + l4 * 4 + r;
    size_t tb = ((size_t)qg * BATCH + b) * K2 + h * HD;
#pragma unroll
    for (int nf = 0; nf < 4; nf++) {
      u16 hh, ll;
      split2(oacc[nf][r] * invl, hh, ll);
      size_t o = tb + nf * 16 + l15;
      A2[o] = hh;
      A2[o + 1024] = ll;
    }
  }
#undef STAGE_K
#undef LOAD_V
#undef SCATTER_V
}

// ---- router: logits, softmax, top-2 (no global atomics) ----
__global__ __launch_bounds__(256)
void router_kernel(const float* __restrict__ x, const float* __restrict__ rw,
                   int* __restrict__ tidx, float* __restrict__ tp) {
  int t = blockIdx.x, tid = threadIdx.x;
  int wid = tid >> 6, lane = tid & 63;
  float4 xv = ((const float4*)(x + (size_t)t * HDIM))[tid];
  __shared__ float part[8][4];
  __shared__ float lg[8];
#pragma unroll
  for (int e = 0; e < 8; e++) {
    float4 wv = ((const float4*)(rw + (size_t)e * HDIM))[tid];
    float d = xv.x * wv.x + xv.y * wv.y + xv.z * wv.z + xv.w * wv.w;
#pragma unroll
    for (int mm = 32; mm >= 1; mm >>= 1) d += __shfl_xor(d, mm);
    if (lane == 0) part[e][wid] = d;
  }
  __syncthreads();
  if (tid < 8) lg[tid] = part[tid][0] + part[tid][1] + part[tid][2] + part[tid][3];
  __syncthreads();
  if (tid == 0) {
    float mx = lg[0];
#pragma unroll
    for (int e = 1; e < 8; e++) mx = fmaxf(mx, lg[e]);
    float g[8]; float se = 0.f;
#pragma unroll
    for (int e = 0; e < 8; e++) { g[e] = __expf(lg[e] - mx); se += g[e]; }
    float inv = 1.0f / se;
#pragma unroll
    for (int e = 0; e < 8; e++) g[e] *= inv;
    int i0 = 0; float v0 = g[0];
#pragma unroll
    for (int e = 1; e < 8; e++) if (g[e] > v0) { v0 = g[e]; i0 = e; }
    int i1 = -1; float v1 = -1.f;
#pragma unroll
    for (int e = 0; e < 8; e++) if (e != i0 && g[e] > v1) { v1 = g[e]; i1 = e; }
    tidx[t * 2] = i0; tidx[t * 2 + 1] = i1;
    tp[t * 2] = v0; tp[t * 2 + 1] = v1;
  }
}

// ---- histogram (expert x rep) + offsets + repBase; zero curRep. One block. ----
__global__ __launch_bounds__(256)
void hist_offsets_kernel(const int* __restrict__ tidx, int* __restrict__ offs,
                         int* __restrict__ repBase, int* __restrict__ curRep) {
  __shared__ int hist[NEXP * NREP];
  __shared__ int eoffs[NEXP + 1];
  int tid = threadIdx.x;
  hist[tid] = 0;
  __syncthreads();
  for (int i = tid; i < TTOK; i += 256) {
    int rep = i & (NREP - 1);
    atomicAdd(&hist[tidx[2 * i] * NREP + rep], 1);
    atomicAdd(&hist[tidx[2 * i + 1] * NREP + rep], 1);
  }
  __syncthreads();
  if (tid == 0) {
    int a = 0;
    for (int e = 0; e < NEXP; e++) {
      eoffs[e] = a;
      for (int r = 0; r < NREP; r++) a += hist[e * NREP + r];
    }
    eoffs[NEXP] = a;
  }
  __syncthreads();
  if (tid < NEXP) {
    int a = eoffs[tid];
    for (int r = 0; r < NREP; r++) {
      repBase[tid * NREP + r] = a;
      a += hist[tid * NREP + r];
    }
  }
  if (tid < NEXP + 1) offs[tid] = eoffs[tid];
  curRep[tid] = 0;
}

// ---- assign: atomics spread over NEXP*NREP counters ----
__global__ __launch_bounds__(256)
void assign_kernel(const int* __restrict__ tidx, const float* __restrict__ tp,
                   const int* __restrict__ repBase, int* __restrict__ curRep,
                   int* __restrict__ rowsIdx, float* __restrict__ wvals,
                   int* __restrict__ inv) {
  int t = blockIdx.x * blockDim.x + threadIdx.x;
  if (t >= TTOK) return;
  int rep = t & (NREP - 1);
#pragma unroll
  for (int k = 0; k < 2; k++) {
    int e = tidx[t * 2 + k];
    int s = atomicAdd(&curRep[e * NREP + rep], 1);
    int pos = repBase[e * NREP + rep] + s;
    rowsIdx[pos] = t;
    wvals[pos] = tp[t * 2 + k];
    inv[t * 2 + k] = pos;
  }
}

__global__ __launch_bounds__(256)
void combine_kernel(float* __restrict__ out, const float* __restrict__ eo,
                    const int* __restrict__ inv) {
  int t = blockIdx.x, c = threadIdx.x;
  int r0 = inv[t * 2], r1 = inv[t * 2 + 1];
  float4* o = (float4*)(out + (size_t)t * HDIM);
  const float4* e0 = (const float4*)(eo + (size_t)r0 * HDIM);
  const float4* e1 = (const float4*)(eo + (size_t)r1 * HDIM);
  float4 v = o[c];
  float4 a = e0[c];
  float4 bb = e1[c];
  v.x += a.x + bb.x; v.y += a.y + bb.y; v.z += a.z + bb.z; v.w += a.w + bb.w;
  o[c] = v;
}

extern "C" void kernel_launch(void* const* d_in, const int* in_sizes, int n_in,
                              void* d_out, int out_size, void* d_ws, size_t ws_size,
                              hipStream_t stream) {
  (void)in_sizes; (void)n_in; (void)out_size; (void)ws_size;
  const float* hs    = (const float*)d_in[0];
  const float* ln1w  = (const float*)d_in[1];
  const float* ln1b  = (const float*)d_in[2];
  const float* ln2w  = (const float*)d_in[3];
  const float* ln2b  = (const float*)d_in[4];
  const float* wqkv  = (const float*)d_in[5];
  const float* wproj = (const float*)d_in[6];
  const float* wrout = (const float*)d_in[7];
  const float* w1    = (const float*)d_in[8];
  const float* w2    = (const float*)d_in[9];
  float* out = (float*)d_out;

  char* base = (char*)d_ws;
  size_t off = 0;
  auto alloc = [&](size_t n) { void* r = base + off; off += (n + 255) & ~(size_t)255; return r; };

  const size_t SZ_W1T   = (size_t)NEXP * FDIM * HDIM * 2;
  const size_t SZ_W2T   = (size_t)NEXP * HDIM * FDIM * 2;
  const size_t SZ_WP2   = (size_t)HDIM * K2 * 2;
  const size_t SZ_LN12  = (size_t)TTOK * K2 * 2;
  const size_t SZ_WQ2   = (size_t)QKVO * K2 * 2;
  const size_t SZ_HMID  = (size_t)TTOK * 2 * FDIM * 2;
  const size_t SZ_Q     = (size_t)BATCH * NHEADS * SLEN * HD * 2;
  const size_t SZ_KV    = (size_t)BATCH * NKV * SLEN * HD * 2;
  const size_t SZ_A2    = (size_t)TTOK * K2 * 2;
  const size_t SZ_EO    = (size_t)TTOK * 2 * HDIM * 4;

  u16* w1t     = (u16*)alloc(SZ_W1T);
  u16* w2t     = (u16*)alloc(SZ_W2T);
  u16* wproj2  = (u16*)alloc(SZ_WP2);

  size_t r1sz = SZ_LN12 + SZ_WQ2;
  if (SZ_HMID > r1sz) r1sz = SZ_HMID;
  char* r1 = (char*)alloc(r1sz);
  u16* ln1_2 = (u16*)r1;
  u16* wqkv2 = (u16*)(r1 + SZ_LN12);
  u16* hmid  = (u16*)r1;

  size_t r2sz = 2 * SZ_Q + 4 * SZ_KV + SZ_A2;
  if (SZ_EO > r2sz) r2sz = SZ_EO;
  char* r2 = (char*)alloc(r2sz);
  u16* Qbh = (u16*)r2;
  u16* Qbl = (u16*)(r2 + SZ_Q);
  u16* Kbh = (u16*)(r2 + 2 * SZ_Q);
  u16* Kbl = (u16*)(r2 + 2 * SZ_Q + SZ_KV);
  u16* Vbh = (u16*)(r2 + 2 * SZ_Q + 2 * SZ_KV);
  u16* Vbl = (u16*)(r2 + 2 * SZ_Q + 3 * SZ_KV);
  u16* attn2 = (u16*)(r2 + 2 * SZ_Q + 4 * SZ_KV);
  float* eo = (float*)r2;

  u16* ln2o    = (u16*)alloc((size_t)TTOK * HDIM * 2);
  float* ln2f  = (float*)alloc((size_t)TTOK * HDIM * 4);
  int* tidx    = (int*)alloc(TTOK * 2 * 4);
  float* tp    = (float*)alloc(TTOK * 2 * 4);
  int* rowsIdx = (int*)alloc(TTOK * 2 * 4);
  float* wvals = (float*)alloc(TTOK * 2 * 4);
  int* invm    = (int*)alloc(TTOK * 2 * 4);
  int* offs    = (int*)alloc((NEXP + 1) * 4);
  int* repBase = (int*)alloc(NEXP * NREP * 4);
  int* curRep  = (int*)alloc(NEXP * NREP * 4);

  // weight prep
  cvt_w2_kernel<<<(QKVO * HDIM / 4 + 255) / 256, 256, 0, stream>>>(wqkv, wqkv2, QKVO * HDIM / 4);
  cvt_w2_kernel<<<(HDIM * HDIM / 4 + 255) / 256, 256, 0, stream>>>(wproj, wproj2, HDIM * HDIM / 4);
  dim3 tb(32, 8);
  transpose_cvt_kernel<<<dim3(FDIM / 32, HDIM / 32, NEXP), tb, 0, stream>>>(w1, w1t, HDIM, FDIM);
  transpose_cvt_kernel<<<dim3(HDIM / 32, FDIM / 32, NEXP), tb, 0, stream>>>(w2, w2t, FDIM, HDIM);

  ln_kernel<<<TTOK, 256, 0, stream>>>(hs, ln1w, ln1b, ln1_2, nullptr, nullptr);

  // QKV: 3-term K-schedule (48 steps over [hi|lo] 2048, A/B restage-skip)
  gemm_bt<0><<<dim3(QKVO / 128, TTOK / 128), 256, 0, stream>>>(
      ln1_2, wqkv2, K2, 48, TTOK, nullptr, nullptr,
      Qbh, Qbl, Kbh, Kbl, Vbh, Vbl, nullptr, nullptr, nullptr);

  attn_kernel<<<dim3(BATCH * NHEADS, SLEN / 64), 256, 0, stream>>>(
      Qbh, Qbl, Kbh, Kbl, Vbh, Vbl, attn2);

  gemm_bt<1><<<dim3(HDIM / 128, TTOK / 128), 256, 0, stream>>>(
      attn2, wproj2, K2, 48, TTOK, hs, out,
      nullptr, nullptr, nullptr, nullptr, nullptr, nullptr, nullptr, nullptr, nullptr);

  ln_kernel<<<TTOK, 256, 0, stream>>>(out, ln2w, ln2b, nullptr, ln2o, ln2f);

  router_kernel<<<TTOK, 256, 0, stream>>>(ln2f, wrout, tidx, tp);
  hist_offsets_kernel<<<1, 256, 0, stream>>>(tidx, offs, repBase, curRep);
  assign_kernel<<<TTOK / 256, 256, 0, stream>>>(tidx, tp, repBase, curRep, rowsIdx, wvals, invm);

  gemm_bt<2><<<dim3(FDIM / 128, TTOK / 128, NEXP), 256, 0, stream>>>(
      ln2o, w1t, HDIM, 16, 0, nullptr, nullptr,
      hmid, nullptr, nullptr, nullptr, nullptr, nullptr, offs, rowsIdx, nullptr);

  gemm_bt<3><<<dim3(HDIM / 128, TTOK / 128, NEXP), 256, 0, stream>>>(
      hmid, w2t, FDIM, 32, 0, nullptr, eo,
      nullptr, nullptr, nullptr, nullptr, nullptr, nullptr, offs, nullptr, wvals);

  combine_kernel<<<TTOK, 256, 0, stream>>>(out, eo, invm);
}